// Round 13
// baseline (865.995 us; speedup 1.0000x reference)
//
#include <hip/hip_runtime.h>
#include <hip/hip_bf16.h>
#include <math.h>

#define T_  64
#define B_  1024
#define E_  300
#define EP_ 320     // E padded to multiple of 32
#define H_  256
#define G3_ 768
#define D_  512
#define CH_ 16      // timesteps per xg chunk / per gru launch

typedef float f32x4 __attribute__((ext_vector_type(4)));
typedef short bf16x8 __attribute__((ext_vector_type(8)));
typedef unsigned short u16x4 __attribute__((ext_vector_type(4)));

__device__ __forceinline__ float bf2f(unsigned short u){ return __uint_as_float(((unsigned)u) << 16); }
__device__ __forceinline__ unsigned short f2bf(float x){
    __hip_bfloat16 h = __float2bfloat16(x);
    return *(unsigned short*)&h;
}
__device__ __forceinline__ float fsig(float x){ return 1.0f/(1.0f + __expf(-x)); }
__device__ __forceinline__ float ftanh(float x){ return 2.0f/(1.0f + __expf(-2.0f*x)) - 1.0f; }

// ---------------------------------------------------------------------------
// centroid -> Lorentz map: su[0:512] = unit*sinh(r), su[512] = cosh(r)
// ---------------------------------------------------------------------------
__global__ void lorentz_u_kernel(const float* __restrict__ centroid,
                                 float* __restrict__ su)
{
    __shared__ float red[512];
    const int tid = threadIdx.x;
    float c = centroid[tid];
    red[tid] = c*c;
    __syncthreads();
    for (int s = 256; s > 0; s >>= 1){
        if (tid < s) red[tid] += red[tid + s];
        __syncthreads();
    }
    float rr = sqrtf(red[0]);
    su[tid] = c / rr * sinhf(rr);
    if (tid == 0) su[512] = coshf(rr);
}

// ---------------------------------------------------------------------------
// fp32 [rows][ncols] -> bf16 [rows][ncols_pad] with zero pad. block=ncols_pad.
// ---------------------------------------------------------------------------
__global__ void cast_pad_kernel(const float* __restrict__ src,
                                __hip_bfloat16* __restrict__ dst,
                                int ncols, int ncols_pad)
{
    long long r = blockIdx.x;
    int c = threadIdx.x;
    float v = (c < ncols) ? src[r*ncols + c] : 0.f;
    dst[r*ncols_pad + c] = __float2bfloat16(v);
}

// ---------------------------------------------------------------------------
// combined input bias: biasc[d][c] = bih_d[c] + (c<512 ? bhh_d[c] : 0)
// ---------------------------------------------------------------------------
__global__ void prep_bias_kernel(const float* __restrict__ bihf, const float* __restrict__ bhhf,
                                 const float* __restrict__ bihb, const float* __restrict__ bhhb,
                                 float* __restrict__ biasc)
{
    int c = threadIdx.x, d = blockIdx.x;
    const float* bih = d ? bihb : bihf;
    const float* bhh = d ? bhhb : bhhf;
    biasc[d*G3_ + c] = bih[c] + (c < 2*H_ ? bhh[c] : 0.f);
}

// ---------------------------------------------------------------------------
// MFMA projection GEMM, both dirs (z). W-RESIDENT + async A double-buffer:
// grid (12, 64, 2), 256 thr. Block stages its 64-col W tile once; loops 4
// row-tiles, with the NEXT tile's gathered rows loaded to registers BEFORE
// the current tile's MFMA (T14 split: latency hides under compute).
// ---------------------------------------------------------------------------
__global__ __launch_bounds__(256) void proj_kernel(
    const int* __restrict__ tokens, int tlo_f, int tlo_b,
    const __hip_bfloat16* __restrict__ embbf,
    const __hip_bfloat16* __restrict__ wihf, const __hip_bfloat16* __restrict__ wihb,
    const float* __restrict__ biasc,
    __hip_bfloat16* __restrict__ xgf, __hip_bfloat16* __restrict__ xgb)
{
    __shared__ char As[64 * 640];   // 40 KB
    __shared__ char Ws[64 * 640];   // 40 KB
    const int dir = blockIdx.z;
    const int tlo = dir ? tlo_b : tlo_f;
    const __hip_bfloat16* Wbf = dir ? wihb : wihf;
    const float* bias = biasc + dir*G3_;
    __hip_bfloat16* xg = dir ? xgb : xgf;
    const int* tok = tokens + (long long)tlo * B_;

    const int tid = threadIdx.x;
    const int n0 = blockIdx.x * 64;
    const int row = tid >> 2, sub = tid & 3;
    const int xm = row & 7;

    {   // stage W tile once (64 cols x 320 k)
        #pragma unroll
        for (int it = 0; it < 10; ++it){
            int idx = it*256 + tid;
            int col = idx / 40, u = idx - col*40;
            float4 v = *(const float4*)(Wbf + (size_t)(n0 + col)*EP_ + u*8);
            *(float4*)(Ws + col*640 + ((u ^ (col & 7)) * 16)) = v;
        }
    }

    const int lane = tid & 63, w = tid >> 6;
    const int g = lane >> 4, l15 = lane & 15;
    const int arow = w*16 + l15;
    const char* abase = As + arow * 640;
    const int amask = arow & 7;

    float4 avA[10], avB[10];
    {   // preload tile 0
        long long tk = tok[blockIdx.y*4*64 + row];
        const char* src = (const char*)(embbf + tk * EP_);
        #pragma unroll
        for (int j = 0; j < 10; ++j)
            avA[j] = *(const float4*)(src + (sub + j*4)*16);
    }

    #pragma unroll
    for (int rt = 0; rt < 4; ++rt){
        const int m0 = (blockIdx.y*4 + rt) * 64;
        float4* avc = (rt & 1) ? avB : avA;
        float4* avn = (rt & 1) ? avA : avB;

        {   // write staged rows to LDS (swizzled)
            char* dst = As + row * 640;
            #pragma unroll
            for (int j = 0; j < 10; ++j)
                *(float4*)(dst + (((sub + j*4) ^ xm) * 16)) = avc[j];
        }
        __syncthreads();   // As ready (Ws too on first iter)

        if (rt < 3){       // issue next tile's loads (hidden under MFMA)
            long long tk = tok[m0 + 64 + row];
            const char* src = (const char*)(embbf + tk * EP_);
            #pragma unroll
            for (int j = 0; j < 10; ++j)
                avn[j] = *(const float4*)(src + (sub + j*4)*16);
        }

        f32x4 acc[4];
        #pragma unroll
        for (int i = 0; i < 4; ++i) acc[i] = (f32x4){0.f,0.f,0.f,0.f};

        #pragma unroll
        for (int kc = 0; kc < 10; ++kc){
            int aslot = kc*4 + g;
            bf16x8 a = *(const bf16x8*)(abase + ((aslot ^ amask) * 16));
            #pragma unroll
            for (int ct = 0; ct < 4; ++ct){
                int cl = ct*16 + l15;
                bf16x8 b = *(const bf16x8*)(Ws + cl*640 + ((aslot ^ (cl & 7)) * 16));
                acc[ct] = __builtin_amdgcn_mfma_f32_16x16x32_bf16(a, b, acc[ct], 0, 0, 0);
            }
        }

        #pragma unroll
        for (int ct = 0; ct < 4; ++ct){
            int col = n0 + ct*16 + l15;
            float bv = bias[col];
            int rbase = m0 + w*16 + g*4;
            #pragma unroll
            for (int i = 0; i < 4; ++i)
                xg[(long long)(rbase + i)*G3_ + col] = __float2bfloat16(acc[ct][i] + bv);
        }
        __syncthreads();   // As consumed before next overwrite
    }
}

// ---------------------------------------------------------------------------
// GRU chunk kernel v7. 128 blocks (dir = bid&1, 16 batch rows), 512 thr
// (8 waves), CH_ steps, ONE barrier/step. Whh register-resident (192 VGPR);
// everything else trimmed to fit the 256-VGPR cap WITHOUT spill:
// hb staged 2-at-a-time, no store batching, hout straight from carry.
// h double-buffered in swizzled LDS; xg double-buffered via global_load_lds.
// ---------------------------------------------------------------------------
__global__ __launch_bounds__(512, 1) void gru_chunk_kernel(
    const __hip_bfloat16* __restrict__ xg_f, const __hip_bfloat16* __restrict__ xg_b,
    int tlo_f, int tlo_b,
    __hip_bfloat16* __restrict__ f_bf,
    float* __restrict__ hf32g,             // [2 dir][B][H] carry between launches
    const float* __restrict__ hidden,
    const __hip_bfloat16* __restrict__ whhbf,  // [2 dir][768][256]
    const float* __restrict__ bhh_f, const float* __restrict__ bhh_b,
    float* __restrict__ hout, int s0)
{
    __shared__ char hlds[2][16 * 512];     // 2 x 8 KB, 16 rows x 256 bf16, swizzled
    __shared__ char xlds[2][16 * 1536];    // 2 x 24 KB, linear rows, rotated units
    __shared__ float blds[256];            // bhh_n for this dir
    const int bid = blockIdx.x;
    const int dir = bid & 1;
    const int b0 = (bid >> 1) * 16;
    const int tid = threadIdx.x;
    const int lane = tid & 63, w = tid >> 6;      // 8 waves
    const int g = lane >> 4, l15 = lane & 15;
    const int jq = w*32 + g*4;

    const __hip_bfloat16* xg = dir ? xg_b : xg_f;
    const int tlo = dir ? tlo_b : tlo_f;
    const float* bhh = dir ? bhh_b : bhh_f;
    const __hip_bfloat16* Wb = whhbf + (size_t)dir * G3_ * H_;
    float* hfg = hf32g + (size_t)dir * B_ * H_;
    const int b = b0 + l15;

    // resident Whh fragments: [gate][tl][kc], 48 x 16B = 192 VGPR
    bf16x8 Wf[3][2][8];
    #pragma unroll
    for (int gate = 0; gate < 3; ++gate)
        #pragma unroll
        for (int tl = 0; tl < 2; ++tl)
            #pragma unroll
            for (int kc = 0; kc < 8; ++kc)
                Wf[gate][tl][kc] = *(const bf16x8*)(Wb +
                    ((size_t)(gate*H_ + w*32 + tl*16 + l15))*H_ + kc*32 + g*8);

    if (tid < 256) blds[tid] = bhh[2*H_ + tid];

    // ---- prologue: h -> hlds[0] + fp32 carry; xg(s0) -> xlds[0] ----
    const float* hsrc = (s0 == 0 ? hidden : hf32g) + (size_t)dir * B_ * H_;
    #pragma unroll
    for (int it = 0; it < 2; ++it){
        int idx = it*512 + tid;            // 1024 = 16 rows x 64 float4
        int r = idx >> 6, q = idx & 63;
        float4 v = *(const float4*)(hsrc + ((size_t)(b0 + r))*H_ + q*4);
        unsigned short t4[4] = { f2bf(v.x), f2bf(v.y), f2bf(v.z), f2bf(v.w) };
        *(uint2*)(hlds[0] + r*512 + (((q>>1) ^ (r&7))*16) + (q&1)*8) = *(uint2*)t4;
    }
    f32x4 carry[2];
    #pragma unroll
    for (int tl = 0; tl < 2; ++tl)
        carry[tl] = *(const f32x4*)&hsrc[(size_t)b*H_ + jq + tl*16];

    // rotation-swizzled async stage: LDS[r][s] = xg_row_r[(s - r) mod 96]
    auto stage_x = [&](char* dst, const __hip_bfloat16* xgt){
        #pragma unroll
        for (int i = 0; i < 3; ++i){
            int U = (i*8 + w)*64 + lane;
            int r = U / 96;
            int sbase = U - r*96;
            int usrc = sbase - r; if (usrc < 0) usrc += 96;
            const char* src = (const char*)xgt + (size_t)(b0 + r)*1536 + usrc*16;
            __builtin_amdgcn_global_load_lds(
                (const __attribute__((address_space(1))) void*)src,
                (__attribute__((address_space(3))) void*)(dst + (i*8 + w)*1024),
                16, 0, 0);
        }
    };
    {
        const int t0 = dir ? (63 - s0) : s0;
        stage_x(xlds[0], xg + (size_t)(t0 - tlo)*B_*G3_);
    }
    __syncthreads();

    int cur = 0, hc = 0;
    for (int s = s0; s < s0 + CH_; ++s){
        const int t = dir ? (63 - s) : s;

        // issue async stage of next step's xg (drains at this step's barrier)
        if (s < s0 + CH_ - 1){
            const int tn = dir ? (t - 1) : (t + 1);
            stage_x(xlds[cur ^ 1], xg + (size_t)(tn - tlo)*B_*G3_);
        }

        f32x4 acc[3][2];
        #pragma unroll
        for (int gate = 0; gate < 3; ++gate)
            #pragma unroll
            for (int tl = 0; tl < 2; ++tl)
                acc[gate][tl] = (f32x4){0.f,0.f,0.f,0.f};

        // hb staged 2-at-a-time (8 VGPR live) — keeps total under the 256 cap
        __builtin_amdgcn_s_setprio(1);
        #pragma unroll
        for (int kh = 0; kh < 4; ++kh){
            bf16x8 hb0 = *(const bf16x8*)(hlds[hc] + l15*512 + ((((2*kh  )*4 + g) ^ (l15&7))*16));
            bf16x8 hb1 = *(const bf16x8*)(hlds[hc] + l15*512 + ((((2*kh+1)*4 + g) ^ (l15&7))*16));
            #pragma unroll
            for (int gate = 0; gate < 3; ++gate)
                #pragma unroll
                for (int tl = 0; tl < 2; ++tl)
                    acc[gate][tl] = __builtin_amdgcn_mfma_f32_16x16x32_bf16(
                        Wf[gate][tl][2*kh], hb0, acc[gate][tl], 0, 0, 0);
            #pragma unroll
            for (int gate = 0; gate < 3; ++gate)
                #pragma unroll
                for (int tl = 0; tl < 2; ++tl)
                    acc[gate][tl] = __builtin_amdgcn_mfma_f32_16x16x32_bf16(
                        Wf[gate][tl][2*kh+1], hb1, acc[gate][tl], 0, 0, 0);
        }
        __builtin_amdgcn_s_setprio(0);

        // epilogue per j-tile (no batching; direct stores)
        #pragma unroll
        for (int tl = 0; tl < 2; ++tl){
            u16x4 xv[3];
            #pragma unroll
            for (int gate = 0; gate < 3; ++gate){
                int u = gate*32 + w*4 + tl*2 + (g >> 1);
                int sl = u + l15; if (sl >= 96) sl -= 96;
                xv[gate] = *(const u16x4*)(xlds[cur] + l15*1536 + sl*16 + (g & 1)*8);
            }
            f32x4 bhn = *(const f32x4*)&blds[jq + tl*16];

            unsigned short hb4[4];
            #pragma unroll
            for (int i = 0; i < 4; ++i){
                float xr = bf2f(xv[0][i]);          // includes bih_r + bhh_r
                float xz = bf2f(xv[1][i]);          // includes bih_z + bhh_z
                float xn = bf2f(xv[2][i]);          // includes bih_n
                float r_ = fsig(xr + acc[0][tl][i]);
                float z_ = fsig(xz + acc[1][tl][i]);
                float n_ = ftanh(xn + r_*(acc[2][tl][i] + bhn[i]));
                float hnew = (1.f - z_)*n_ + z_*carry[tl][i];
                carry[tl][i] = hnew;
                hb4[i] = f2bf(hnew);
            }
            int j0 = jq + tl*16;
            int slot = j0 >> 3;
            *(uint2*)(hlds[hc^1] + l15*512 + ((slot ^ (l15&7))*16) + (j0&7)*2) = *(uint2*)hb4;
            *(u16x4*)((char*)f_bf + (((size_t)t*B_ + b)*D_ + dir*H_ + j0)*2) = *(u16x4*)hb4;
            if (s == 63)
                *(f32x4*)&hout[(size_t)dir*B_*H_ + (size_t)b*H_ + j0] = carry[tl];
        }

        __syncthreads();   // drains ds writes + async xg stage + stores
        cur ^= 1; hc ^= 1;
    }

    // persist fp32 carry
    #pragma unroll
    for (int tl = 0; tl < 2; ++tl)
        *(f32x4*)&hfg[(size_t)b*H_ + jq + tl*16] = carry[tl];
}

// ---------------------------------------------------------------------------
// MFMA attention GEMM + fused tanh/Lorentz score + rr2. 1024 blocks x 256 thr,
// 64 rows/block. W streamed in 16 chunks of 32 cols through DOUBLE-BUFFERED
// LDS (2 x 32 KB) via async global_load_lds, rotation-swizzled source.
// ---------------------------------------------------------------------------
__global__ __launch_bounds__(256) void attn_score_kernel(
    const __hip_bfloat16* __restrict__ f_bf, const __hip_bfloat16* __restrict__ Wbf,
    const float* __restrict__ attn_b, const float* __restrict__ su,
    const float* __restrict__ beta, float* __restrict__ score,
    float* __restrict__ rr2)
{
    __shared__ char WL[2][32 * 1024];   // 2 x 32 KB: 32 cols x 64 units x 16B
    const int tid = threadIdx.x;
    const int lane = tid & 63, w = tid >> 6;
    const int g = lane >> 4, l15 = lane & 15;
    const long long m0 = (long long)blockIdx.x * 64;
    const long long arow = m0 + w*16 + l15;

    bf16x8 a[16];
    const __hip_bfloat16* ap = f_bf + arow*D_;
    #pragma unroll
    for (int kc = 0; kc < 16; ++kc)
        a[kc] = *(const bf16x8*)(ap + kc*32 + g*8);

    // rr2 = sum over row of f^2
    {
        float s2 = 0.f;
        #pragma unroll
        for (int kc = 0; kc < 16; ++kc){
            const unsigned short* hb = (const unsigned short*)&a[kc];
            #pragma unroll
            for (int q = 0; q < 8; ++q){ float x = bf2f(hb[q]); s2 += x*x; }
        }
        s2 += __shfl_xor(s2, 16);
        s2 += __shfl_xor(s2, 32);
        if (g == 0) rr2[arow] = s2;
    }

    // async W chunk stage: LDS unit U=(col,slot); source unit usrc=(slot-col)&63
    auto stage_w = [&](char* dst, int nc){
        const __hip_bfloat16* wsrc = Wbf + (size_t)nc*32*D_;
        #pragma unroll
        for (int i = 0; i < 8; ++i){
            int U = i*256 + tid;
            int r = U >> 6, sl = U & 63;
            int usrc = (sl - r) & 63;
            const char* src = (const char*)(wsrc + (size_t)r*D_) + usrc*16;
            __builtin_amdgcn_global_load_lds(
                (const __attribute__((address_space(1))) void*)src,
                (__attribute__((address_space(3))) void*)(dst + U*16),
                16, 0, 0);
        }
    };

    stage_w(WL[0], 0);
    __syncthreads();

    float pdot[4] = {0,0,0,0}, pa2[4] = {0,0,0,0};
    int cur = 0;

    for (int nc = 0; nc < 16; ++nc){
        if (nc < 15) stage_w(WL[cur ^ 1], nc + 1);

        f32x4 acc[2];
        acc[0] = (f32x4){0.f,0.f,0.f,0.f};
        acc[1] = (f32x4){0.f,0.f,0.f,0.f};
        #pragma unroll
        for (int kc = 0; kc < 16; ++kc){
            int u = kc*4 + g;
            #pragma unroll
            for (int ct = 0; ct < 2; ++ct){
                int cl = ct*16 + l15;
                bf16x8 bfr = *(const bf16x8*)(WL[cur] + cl*1024 + (((u + cl) & 63)*16));
                acc[ct] = __builtin_amdgcn_mfma_f32_16x16x32_bf16(a[kc], bfr, acc[ct], 0, 0, 0);
            }
        }

        #pragma unroll
        for (int ct = 0; ct < 2; ++ct){
            int col = nc*32 + ct*16 + l15;
            float bc = attn_b[col], sc = su[col];
            #pragma unroll
            for (int i = 0; i < 4; ++i){
                float av = ftanh(acc[ct][i] + bc);
                pdot[i] += av*sc;
                pa2[i]  += av*av;
            }
        }

        __syncthreads();   // drains async stage + all waves done with WL[cur]
        cur ^= 1;
    }

    #pragma unroll
    for (int m = 1; m < 16; m <<= 1){
        #pragma unroll
        for (int i = 0; i < 4; ++i){
            pdot[i] += __shfl_xor(pdot[i], m);
            pa2[i]  += __shfl_xor(pa2[i],  m);
        }
    }
    if (l15 == 0){
        const float cu = su[512], bb = beta[0];
        #pragma unroll
        for (int i = 0; i < 4; ++i){
            long long row = m0 + w*16 + g*4 + i;
            float ra  = sqrtf(pa2[i]);
            float shc = sinhf(ra)/ra;
            float prod = cu*coshf(ra) - shc*pdot[i];
            prod = fminf(fmaxf(prod, 1.0f + 1e-7f), 1e16f);
            float dist = logf(prod) + log1pf(sqrtf(prod*prod - 1.0f + 1e-7f)/prod);
            score[row] = -bb * dist;
        }
    }
}

// ---------------------------------------------------------------------------
// per-batch softmax over T, gamma weighting, weighted fK sum (bf16 f input).
// ---------------------------------------------------------------------------
__global__ __launch_bounds__(256) void pool_kernel(
    const __hip_bfloat16* __restrict__ f_bf, const float* __restrict__ score,
    const float* __restrict__ rr2, float* __restrict__ out)
{
    __shared__ float wss[64];
    const int tid = threadIdx.x;
    const long long b = blockIdx.x;

    if (tid < 64){
        int t = tid;
        float sc = score[t*B_ + b];
        float mx = sc;
        #pragma unroll
        for (int m = 1; m < 64; m <<= 1) mx = fmaxf(mx, __shfl_xor(mx, m));
        float e = expf(sc - mx);
        float rr = sqrtf(rr2[t*B_ + b]);
        float th = tanhf(rr);
        float omt = 1.0f - th*th;
        omt = fminf(fmaxf(omt, 1e-7f), 1.0f - 1e-7f);
        float gamma = 1.0f / sqrtf(omt);
        gamma = fminf(fmaxf(gamma, 1.0f + 1e-7f), 1e16f);
        float wgt = e * gamma;
        float ssum = wgt;
        #pragma unroll
        for (int m = 1; m < 64; m <<= 1) ssum += __shfl_xor(ssum, m);
        wss[t] = (wgt / ssum) * (th / rr);
    }
    __syncthreads();

    #pragma unroll
    for (int dd = 0; dd < 2; ++dd){
        int d = tid + dd*256;
        float acc = 0.f;
        for (int t = 0; t < 64; ++t)
            acc += wss[t] * __bfloat162float(f_bf[((long long)t*B_ + b)*D_ + d]);
        out[b*D_ + d] = acc;
    }
}

// ---------------------------------------------------------------------------
extern "C" void kernel_launch(void* const* d_in, const int* in_sizes, int n_in,
                              void* d_out, int out_size, void* d_ws, size_t ws_size,
                              hipStream_t stream)
{
    const int*   tokens = (const int*)  d_in[0];
    const float* hidden = (const float*)d_in[1];
    const float* emb    = (const float*)d_in[2];
    const float* Wih_f  = (const float*)d_in[3];
    const float* Whh_f  = (const float*)d_in[4];
    const float* bih_f  = (const float*)d_in[5];
    const float* bhh_f  = (const float*)d_in[6];
    const float* Wih_b  = (const float*)d_in[7];
    const float* Whh_b  = (const float*)d_in[8];
    const float* bih_b  = (const float*)d_in[9];
    const float* bhh_b  = (const float*)d_in[10];
    const float* attn_W = (const float*)d_in[11];
    const float* attn_b = (const float*)d_in[12];
    const float* centroid = (const float*)d_in[13];
    const float* beta   = (const float*)d_in[14];

    const int V = in_sizes[2] / E_;

    char* w = (char*)d_ws;
    __hip_bfloat16* f_bf  = (__hip_bfloat16*)w;  w += (size_t)T_*B_*D_*2;      // 64 MiB
    __hip_bfloat16* xg_f  = (__hip_bfloat16*)w;  w += (size_t)CH_*B_*G3_*2;    // 24 MiB
    __hip_bfloat16* xg_b  = (__hip_bfloat16*)w;  w += (size_t)CH_*B_*G3_*2;    // 24 MiB
    float*          hf32g = (float*)w;           w += (size_t)2*B_*H_*4;       // 2 MiB
    __hip_bfloat16* embbf = (__hip_bfloat16*)w;  w += (size_t)V*EP_*2;         // 30.5 MiB
    __hip_bfloat16* wihf  = (__hip_bfloat16*)w;  w += (size_t)G3_*EP_*2;
    __hip_bfloat16* wihb  = (__hip_bfloat16*)w;  w += (size_t)G3_*EP_*2;
    __hip_bfloat16* whhbf = (__hip_bfloat16*)w;  w += (size_t)2*G3_*H_*2;
    __hip_bfloat16* wat   = (__hip_bfloat16*)w;  w += (size_t)D_*D_*2;
    float*          biasc = (float*)w;           w += (size_t)2*G3_*4;
    float*          score = (float*)w;           w += (size_t)T_*B_*4;
    float*          rr2   = (float*)w;           w += (size_t)T_*B_*4;
    float*          su    = (float*)w;           w += 513*4;

    float* out  = (float*)d_out;                 // B*512
    float* hout = out + (long long)B_*D_;        // 2*B*256

    lorentz_u_kernel<<<1, 512, 0, stream>>>(centroid, su);
    prep_bias_kernel<<<2, G3_, 0, stream>>>(bih_f, bhh_f, bih_b, bhh_b, biasc);
    cast_pad_kernel<<<V,   EP_, 0, stream>>>(emb,    embbf, E_, EP_);
    cast_pad_kernel<<<G3_, EP_, 0, stream>>>(Wih_f,  wihf,  E_, EP_);
    cast_pad_kernel<<<G3_, EP_, 0, stream>>>(Wih_b,  wihb,  E_, EP_);
    cast_pad_kernel<<<G3_, H_,  0, stream>>>(Whh_f,  whhbf,            H_, H_);
    cast_pad_kernel<<<G3_, H_,  0, stream>>>(Whh_b,  whhbf + (size_t)G3_*H_, H_, H_);
    cast_pad_kernel<<<D_,  D_,  0, stream>>>(attn_W, wat,   D_, D_);

    for (int c = 0; c < T_/CH_; ++c){
        int tlo_f = c*CH_;
        int tlo_b = (T_ - CH_) - c*CH_;
        int s0 = c*CH_;
        proj_kernel<<<dim3(12, 64, 2), 256, 0, stream>>>(
            tokens, tlo_f, tlo_b, embbf, wihf, wihb, biasc, xg_f, xg_b);
        gru_chunk_kernel<<<128, 512, 0, stream>>>(
            xg_f, xg_b, tlo_f, tlo_b, f_bf, hf32g, hidden,
            whhbf, bhh_f, bhh_b, hout, s0);
    }

    attn_score_kernel<<<1024, 256, 0, stream>>>(f_bf, wat, attn_b, su, beta, score, rr2);
    pool_kernel<<<1024, 256, 0, stream>>>(f_bf, score, rr2, out);
}

// Round 14
// 617.132 us; speedup vs baseline: 1.4033x; 1.4033x over previous
//
#include <hip/hip_runtime.h>
#include <hip/hip_bf16.h>
#include <math.h>

#define T_  64
#define B_  1024
#define E_  300
#define EP_ 320     // E padded to multiple of 32
#define H_  256
#define G3_ 768
#define D_  512
#define CH_ 16      // timesteps per xg chunk / per gru launch

typedef float f32x4 __attribute__((ext_vector_type(4)));
typedef short bf16x8 __attribute__((ext_vector_type(8)));
typedef unsigned short u16x4 __attribute__((ext_vector_type(4)));

__device__ __forceinline__ float bf2f(unsigned short u){ return __uint_as_float(((unsigned)u) << 16); }
__device__ __forceinline__ unsigned short f2bf(float x){
    __hip_bfloat16 h = __float2bfloat16(x);
    return *(unsigned short*)&h;
}
__device__ __forceinline__ float fsig(float x){ return 1.0f/(1.0f + __expf(-x)); }
__device__ __forceinline__ float ftanh(float x){ return 2.0f/(1.0f + __expf(-2.0f*x)) - 1.0f; }

// ---------------------------------------------------------------------------
// centroid -> Lorentz map: su[0:512] = unit*sinh(r), su[512] = cosh(r)
// ---------------------------------------------------------------------------
__global__ void lorentz_u_kernel(const float* __restrict__ centroid,
                                 float* __restrict__ su)
{
    __shared__ float red[512];
    const int tid = threadIdx.x;
    float c = centroid[tid];
    red[tid] = c*c;
    __syncthreads();
    for (int s = 256; s > 0; s >>= 1){
        if (tid < s) red[tid] += red[tid + s];
        __syncthreads();
    }
    float rr = sqrtf(red[0]);
    su[tid] = c / rr * sinhf(rr);
    if (tid == 0) su[512] = coshf(rr);
}

// ---------------------------------------------------------------------------
// fp32 [rows][ncols] -> bf16 [rows][ncols_pad] with zero pad. block=ncols_pad.
// ---------------------------------------------------------------------------
__global__ void cast_pad_kernel(const float* __restrict__ src,
                                __hip_bfloat16* __restrict__ dst,
                                int ncols, int ncols_pad)
{
    long long r = blockIdx.x;
    int c = threadIdx.x;
    float v = (c < ncols) ? src[r*ncols + c] : 0.f;
    dst[r*ncols_pad + c] = __float2bfloat16(v);
}

// ---------------------------------------------------------------------------
// combined input bias: biasc[d][c] = bih_d[c] + (c<512 ? bhh_d[c] : 0)
// ---------------------------------------------------------------------------
__global__ void prep_bias_kernel(const float* __restrict__ bihf, const float* __restrict__ bhhf,
                                 const float* __restrict__ bihb, const float* __restrict__ bhhb,
                                 float* __restrict__ biasc)
{
    int c = threadIdx.x, d = blockIdx.x;
    const float* bih = d ? bihb : bihf;
    const float* bhh = d ? bhhb : bhhf;
    biasc[d*G3_ + c] = bih[c] + (c < 2*H_ ? bhh[c] : 0.f);
}

// ---------------------------------------------------------------------------
// MFMA projection GEMM, both dirs (z). W-RESIDENT: grid (12, 64, 2), 256 thr.
// Each block stages its 64-col W tile (40 KB) ONCE into swizzled LDS, then
// loops 4 row-tiles of 64 gathered emb rows. K = 320. bf16 out.
// (Round-12 version: NO register prefetch — the r13 prefetch spilled.)
// ---------------------------------------------------------------------------
__global__ __launch_bounds__(256) void proj_kernel(
    const int* __restrict__ tokens, int tlo_f, int tlo_b,
    const __hip_bfloat16* __restrict__ embbf,
    const __hip_bfloat16* __restrict__ wihf, const __hip_bfloat16* __restrict__ wihb,
    const float* __restrict__ biasc,
    __hip_bfloat16* __restrict__ xgf, __hip_bfloat16* __restrict__ xgb)
{
    __shared__ char As[64 * 640];   // 40 KB: 64 rows x 320 bf16, swizzled 16B units
    __shared__ char Ws[64 * 640];   // 40 KB: 64 cols x 320 bf16, swizzled 16B units
    const int dir = blockIdx.z;
    const int tlo = dir ? tlo_b : tlo_f;
    const __hip_bfloat16* Wbf = dir ? wihb : wihf;
    const float* bias = biasc + dir*G3_;
    __hip_bfloat16* xg = dir ? xgb : xgf;
    const int* tok = tokens + (long long)tlo * B_;

    const int tid = threadIdx.x;
    const int n0 = blockIdx.x * 64;

    {   // stage W tile once (64 cols x 320 k): 2560 units, 10 rounds
        #pragma unroll
        for (int it = 0; it < 10; ++it){
            int idx = it*256 + tid;
            int col = idx / 40, u = idx - col*40;
            float4 v = *(const float4*)(Wbf + (size_t)(n0 + col)*EP_ + u*8);
            *(float4*)(Ws + col*640 + ((u ^ (col & 7)) * 16)) = v;
        }
    }

    const int lane = tid & 63, w = tid >> 6;
    const int g = lane >> 4, l15 = lane & 15;
    const int arow = w*16 + l15;
    const char* abase = As + arow * 640;
    const int amask = arow & 7;

    for (int rt = 0; rt < 4; ++rt){
        const int m0 = (blockIdx.y*4 + rt) * 64;
        {   // stage gathered emb rows
            int row = tid >> 2, sub = tid & 3;
            long long tk = tok[m0 + row];
            const char* src = (const char*)(embbf + tk * EP_);
            char* dst = As + row * 640;
            int xm = (row & 7);
            #pragma unroll
            for (int j = 0; j < 10; ++j){
                int slot = sub + j*4;
                float4 v = *(const float4*)(src + slot*16);
                *(float4*)(dst + ((slot ^ xm) * 16)) = v;
            }
        }
        __syncthreads();   // As ready (and Ws on first iteration)

        f32x4 acc[4];
        #pragma unroll
        for (int i = 0; i < 4; ++i) acc[i] = (f32x4){0.f,0.f,0.f,0.f};

        #pragma unroll
        for (int kc = 0; kc < 10; ++kc){
            int aslot = kc*4 + g;
            bf16x8 a = *(const bf16x8*)(abase + ((aslot ^ amask) * 16));
            #pragma unroll
            for (int ct = 0; ct < 4; ++ct){
                int cl = ct*16 + l15;
                bf16x8 b = *(const bf16x8*)(Ws + cl*640 + ((aslot ^ (cl & 7)) * 16));
                acc[ct] = __builtin_amdgcn_mfma_f32_16x16x32_bf16(a, b, acc[ct], 0, 0, 0);
            }
        }

        #pragma unroll
        for (int ct = 0; ct < 4; ++ct){
            int col = n0 + ct*16 + l15;
            float bv = bias[col];
            int rbase = m0 + w*16 + g*4;
            #pragma unroll
            for (int i = 0; i < 4; ++i)
                xg[(long long)(rbase + i)*G3_ + col] = __float2bfloat16(acc[ct][i] + bv);
        }
        __syncthreads();   // done reading As before next overwrite
    }
}

// ---------------------------------------------------------------------------
// GRU chunk kernel v7. 128 blocks (dir = bid&1, 16 batch rows), 512 thr
// (8 waves), CH_ steps, ONE barrier/step. Whh register-resident (192 VGPR);
// hb staged 2-at-a-time, no store batching, hout straight from carry.
// h double-buffered in swizzled LDS; xg double-buffered via global_load_lds.
// ---------------------------------------------------------------------------
__global__ __launch_bounds__(512, 1) void gru_chunk_kernel(
    const __hip_bfloat16* __restrict__ xg_f, const __hip_bfloat16* __restrict__ xg_b,
    int tlo_f, int tlo_b,
    __hip_bfloat16* __restrict__ f_bf,
    float* __restrict__ hf32g,             // [2 dir][B][H] carry between launches
    const float* __restrict__ hidden,
    const __hip_bfloat16* __restrict__ whhbf,  // [2 dir][768][256]
    const float* __restrict__ bhh_f, const float* __restrict__ bhh_b,
    float* __restrict__ hout, int s0)
{
    __shared__ char hlds[2][16 * 512];     // 2 x 8 KB, 16 rows x 256 bf16, swizzled
    __shared__ char xlds[2][16 * 1536];    // 2 x 24 KB, linear rows, rotated units
    __shared__ float blds[256];            // bhh_n for this dir
    const int bid = blockIdx.x;
    const int dir = bid & 1;
    const int b0 = (bid >> 1) * 16;
    const int tid = threadIdx.x;
    const int lane = tid & 63, w = tid >> 6;      // 8 waves
    const int g = lane >> 4, l15 = lane & 15;
    const int jq = w*32 + g*4;

    const __hip_bfloat16* xg = dir ? xg_b : xg_f;
    const int tlo = dir ? tlo_b : tlo_f;
    const float* bhh = dir ? bhh_b : bhh_f;
    const __hip_bfloat16* Wb = whhbf + (size_t)dir * G3_ * H_;
    float* hfg = hf32g + (size_t)dir * B_ * H_;
    const int b = b0 + l15;

    // resident Whh fragments: [gate][tl][kc], 48 x 16B = 192 VGPR
    bf16x8 Wf[3][2][8];
    #pragma unroll
    for (int gate = 0; gate < 3; ++gate)
        #pragma unroll
        for (int tl = 0; tl < 2; ++tl)
            #pragma unroll
            for (int kc = 0; kc < 8; ++kc)
                Wf[gate][tl][kc] = *(const bf16x8*)(Wb +
                    ((size_t)(gate*H_ + w*32 + tl*16 + l15))*H_ + kc*32 + g*8);

    if (tid < 256) blds[tid] = bhh[2*H_ + tid];

    // ---- prologue: h -> hlds[0] + fp32 carry; xg(s0) -> xlds[0] ----
    const float* hsrc = (s0 == 0 ? hidden : hf32g) + (size_t)dir * B_ * H_;
    #pragma unroll
    for (int it = 0; it < 2; ++it){
        int idx = it*512 + tid;            // 1024 = 16 rows x 64 float4
        int r = idx >> 6, q = idx & 63;
        float4 v = *(const float4*)(hsrc + ((size_t)(b0 + r))*H_ + q*4);
        unsigned short t4[4] = { f2bf(v.x), f2bf(v.y), f2bf(v.z), f2bf(v.w) };
        *(uint2*)(hlds[0] + r*512 + (((q>>1) ^ (r&7))*16) + (q&1)*8) = *(uint2*)t4;
    }
    f32x4 carry[2];
    #pragma unroll
    for (int tl = 0; tl < 2; ++tl)
        carry[tl] = *(const f32x4*)&hsrc[(size_t)b*H_ + jq + tl*16];

    // rotation-swizzled async stage: LDS[r][s] = xg_row_r[(s - r) mod 96]
    auto stage_x = [&](char* dst, const __hip_bfloat16* xgt){
        #pragma unroll
        for (int i = 0; i < 3; ++i){
            int U = (i*8 + w)*64 + lane;
            int r = U / 96;
            int sbase = U - r*96;
            int usrc = sbase - r; if (usrc < 0) usrc += 96;
            const char* src = (const char*)xgt + (size_t)(b0 + r)*1536 + usrc*16;
            __builtin_amdgcn_global_load_lds(
                (const __attribute__((address_space(1))) void*)src,
                (__attribute__((address_space(3))) void*)(dst + (i*8 + w)*1024),
                16, 0, 0);
        }
    };
    {
        const int t0 = dir ? (63 - s0) : s0;
        stage_x(xlds[0], xg + (size_t)(t0 - tlo)*B_*G3_);
    }
    __syncthreads();

    int cur = 0, hc = 0;
    for (int s = s0; s < s0 + CH_; ++s){
        const int t = dir ? (63 - s) : s;

        // issue async stage of next step's xg (drains at this step's barrier)
        if (s < s0 + CH_ - 1){
            const int tn = dir ? (t - 1) : (t + 1);
            stage_x(xlds[cur ^ 1], xg + (size_t)(tn - tlo)*B_*G3_);
        }

        f32x4 acc[3][2];
        #pragma unroll
        for (int gate = 0; gate < 3; ++gate)
            #pragma unroll
            for (int tl = 0; tl < 2; ++tl)
                acc[gate][tl] = (f32x4){0.f,0.f,0.f,0.f};

        // hb staged 2-at-a-time (8 VGPR live) — keeps total under the 256 cap
        __builtin_amdgcn_s_setprio(1);
        #pragma unroll
        for (int kh = 0; kh < 4; ++kh){
            bf16x8 hb0 = *(const bf16x8*)(hlds[hc] + l15*512 + ((((2*kh  )*4 + g) ^ (l15&7))*16));
            bf16x8 hb1 = *(const bf16x8*)(hlds[hc] + l15*512 + ((((2*kh+1)*4 + g) ^ (l15&7))*16));
            #pragma unroll
            for (int gate = 0; gate < 3; ++gate)
                #pragma unroll
                for (int tl = 0; tl < 2; ++tl)
                    acc[gate][tl] = __builtin_amdgcn_mfma_f32_16x16x32_bf16(
                        Wf[gate][tl][2*kh], hb0, acc[gate][tl], 0, 0, 0);
            #pragma unroll
            for (int gate = 0; gate < 3; ++gate)
                #pragma unroll
                for (int tl = 0; tl < 2; ++tl)
                    acc[gate][tl] = __builtin_amdgcn_mfma_f32_16x16x32_bf16(
                        Wf[gate][tl][2*kh+1], hb1, acc[gate][tl], 0, 0, 0);
        }
        __builtin_amdgcn_s_setprio(0);

        // epilogue per j-tile (no batching; direct stores)
        #pragma unroll
        for (int tl = 0; tl < 2; ++tl){
            u16x4 xv[3];
            #pragma unroll
            for (int gate = 0; gate < 3; ++gate){
                int u = gate*32 + w*4 + tl*2 + (g >> 1);
                int sl = u + l15; if (sl >= 96) sl -= 96;
                xv[gate] = *(const u16x4*)(xlds[cur] + l15*1536 + sl*16 + (g & 1)*8);
            }
            f32x4 bhn = *(const f32x4*)&blds[jq + tl*16];

            unsigned short hb4[4];
            #pragma unroll
            for (int i = 0; i < 4; ++i){
                float xr = bf2f(xv[0][i]);          // includes bih_r + bhh_r
                float xz = bf2f(xv[1][i]);          // includes bih_z + bhh_z
                float xn = bf2f(xv[2][i]);          // includes bih_n
                float r_ = fsig(xr + acc[0][tl][i]);
                float z_ = fsig(xz + acc[1][tl][i]);
                float n_ = ftanh(xn + r_*(acc[2][tl][i] + bhn[i]));
                float hnew = (1.f - z_)*n_ + z_*carry[tl][i];
                carry[tl][i] = hnew;
                hb4[i] = f2bf(hnew);
            }
            int j0 = jq + tl*16;
            int slot = j0 >> 3;
            *(uint2*)(hlds[hc^1] + l15*512 + ((slot ^ (l15&7))*16) + (j0&7)*2) = *(uint2*)hb4;
            *(u16x4*)((char*)f_bf + (((size_t)t*B_ + b)*D_ + dir*H_ + j0)*2) = *(u16x4*)hb4;
            if (s == 63)
                *(f32x4*)&hout[(size_t)dir*B_*H_ + (size_t)b*H_ + j0] = carry[tl];
        }

        __syncthreads();   // drains ds writes + async xg stage + stores
        cur ^= 1; hc ^= 1;
    }

    // persist fp32 carry
    #pragma unroll
    for (int tl = 0; tl < 2; ++tl)
        *(f32x4*)&hfg[(size_t)b*H_ + jq + tl*16] = carry[tl];
}

// ---------------------------------------------------------------------------
// MFMA attention GEMM + fused tanh/Lorentz score + rr2. 1024 blocks x 256 thr,
// 64 rows/block. W streamed in 16 chunks of 32 cols through DOUBLE-BUFFERED
// LDS (2 x 32 KB) via async global_load_lds, rotation-swizzled source.
// ---------------------------------------------------------------------------
__global__ __launch_bounds__(256) void attn_score_kernel(
    const __hip_bfloat16* __restrict__ f_bf, const __hip_bfloat16* __restrict__ Wbf,
    const float* __restrict__ attn_b, const float* __restrict__ su,
    const float* __restrict__ beta, float* __restrict__ score,
    float* __restrict__ rr2)
{
    __shared__ char WL[2][32 * 1024];   // 2 x 32 KB: 32 cols x 64 units x 16B
    const int tid = threadIdx.x;
    const int lane = tid & 63, w = tid >> 6;
    const int g = lane >> 4, l15 = lane & 15;
    const long long m0 = (long long)blockIdx.x * 64;
    const long long arow = m0 + w*16 + l15;

    bf16x8 a[16];
    const __hip_bfloat16* ap = f_bf + arow*D_;
    #pragma unroll
    for (int kc = 0; kc < 16; ++kc)
        a[kc] = *(const bf16x8*)(ap + kc*32 + g*8);

    // rr2 = sum over row of f^2
    {
        float s2 = 0.f;
        #pragma unroll
        for (int kc = 0; kc < 16; ++kc){
            const unsigned short* hb = (const unsigned short*)&a[kc];
            #pragma unroll
            for (int q = 0; q < 8; ++q){ float x = bf2f(hb[q]); s2 += x*x; }
        }
        s2 += __shfl_xor(s2, 16);
        s2 += __shfl_xor(s2, 32);
        if (g == 0) rr2[arow] = s2;
    }

    // async W chunk stage: LDS unit U=(col,slot); source unit usrc=(slot-col)&63
    auto stage_w = [&](char* dst, int nc){
        const __hip_bfloat16* wsrc = Wbf + (size_t)nc*32*D_;
        #pragma unroll
        for (int i = 0; i < 8; ++i){
            int U = i*256 + tid;
            int r = U >> 6, sl = U & 63;
            int usrc = (sl - r) & 63;
            const char* src = (const char*)(wsrc + (size_t)r*D_) + usrc*16;
            __builtin_amdgcn_global_load_lds(
                (const __attribute__((address_space(1))) void*)src,
                (__attribute__((address_space(3))) void*)(dst + U*16),
                16, 0, 0);
        }
    };

    stage_w(WL[0], 0);
    __syncthreads();

    float pdot[4] = {0,0,0,0}, pa2[4] = {0,0,0,0};
    int cur = 0;

    for (int nc = 0; nc < 16; ++nc){
        if (nc < 15) stage_w(WL[cur ^ 1], nc + 1);

        f32x4 acc[2];
        acc[0] = (f32x4){0.f,0.f,0.f,0.f};
        acc[1] = (f32x4){0.f,0.f,0.f,0.f};
        #pragma unroll
        for (int kc = 0; kc < 16; ++kc){
            int u = kc*4 + g;
            #pragma unroll
            for (int ct = 0; ct < 2; ++ct){
                int cl = ct*16 + l15;
                bf16x8 bfr = *(const bf16x8*)(WL[cur] + cl*1024 + (((u + cl) & 63)*16));
                acc[ct] = __builtin_amdgcn_mfma_f32_16x16x32_bf16(a[kc], bfr, acc[ct], 0, 0, 0);
            }
        }

        #pragma unroll
        for (int ct = 0; ct < 2; ++ct){
            int col = nc*32 + ct*16 + l15;
            float bc = attn_b[col], sc = su[col];
            #pragma unroll
            for (int i = 0; i < 4; ++i){
                float av = ftanh(acc[ct][i] + bc);
                pdot[i] += av*sc;
                pa2[i]  += av*av;
            }
        }

        __syncthreads();   // drains async stage + all waves done with WL[cur]
        cur ^= 1;
    }

    #pragma unroll
    for (int m = 1; m < 16; m <<= 1){
        #pragma unroll
        for (int i = 0; i < 4; ++i){
            pdot[i] += __shfl_xor(pdot[i], m);
            pa2[i]  += __shfl_xor(pa2[i],  m);
        }
    }
    if (l15 == 0){
        const float cu = su[512], bb = beta[0];
        #pragma unroll
        for (int i = 0; i < 4; ++i){
            long long row = m0 + w*16 + g*4 + i;
            float ra  = sqrtf(pa2[i]);
            float shc = sinhf(ra)/ra;
            float prod = cu*coshf(ra) - shc*pdot[i];
            prod = fminf(fmaxf(prod, 1.0f + 1e-7f), 1e16f);
            float dist = logf(prod) + log1pf(sqrtf(prod*prod - 1.0f + 1e-7f)/prod);
            score[row] = -bb * dist;
        }
    }
}

// ---------------------------------------------------------------------------
// per-batch softmax over T, gamma weighting, weighted fK sum (bf16 f input).
// ---------------------------------------------------------------------------
__global__ __launch_bounds__(256) void pool_kernel(
    const __hip_bfloat16* __restrict__ f_bf, const float* __restrict__ score,
    const float* __restrict__ rr2, float* __restrict__ out)
{
    __shared__ float wss[64];
    const int tid = threadIdx.x;
    const long long b = blockIdx.x;

    if (tid < 64){
        int t = tid;
        float sc = score[t*B_ + b];
        float mx = sc;
        #pragma unroll
        for (int m = 1; m < 64; m <<= 1) mx = fmaxf(mx, __shfl_xor(mx, m));
        float e = expf(sc - mx);
        float rr = sqrtf(rr2[t*B_ + b]);
        float th = tanhf(rr);
        float omt = 1.0f - th*th;
        omt = fminf(fmaxf(omt, 1e-7f), 1.0f - 1e-7f);
        float gamma = 1.0f / sqrtf(omt);
        gamma = fminf(fmaxf(gamma, 1.0f + 1e-7f), 1e16f);
        float wgt = e * gamma;
        float ssum = wgt;
        #pragma unroll
        for (int m = 1; m < 64; m <<= 1) ssum += __shfl_xor(ssum, m);
        wss[t] = (wgt / ssum) * (th / rr);
    }
    __syncthreads();

    #pragma unroll
    for (int dd = 0; dd < 2; ++dd){
        int d = tid + dd*256;
        float acc = 0.f;
        for (int t = 0; t < 64; ++t)
            acc += wss[t] * __bfloat162float(f_bf[((long long)t*B_ + b)*D_ + d]);
        out[b*D_ + d] = acc;
    }
}

// ---------------------------------------------------------------------------
extern "C" void kernel_launch(void* const* d_in, const int* in_sizes, int n_in,
                              void* d_out, int out_size, void* d_ws, size_t ws_size,
                              hipStream_t stream)
{
    const int*   tokens = (const int*)  d_in[0];
    const float* hidden = (const float*)d_in[1];
    const float* emb    = (const float*)d_in[2];
    const float* Wih_f  = (const float*)d_in[3];
    const float* Whh_f  = (const float*)d_in[4];
    const float* bih_f  = (const float*)d_in[5];
    const float* bhh_f  = (const float*)d_in[6];
    const float* Wih_b  = (const float*)d_in[7];
    const float* Whh_b  = (const float*)d_in[8];
    const float* bih_b  = (const float*)d_in[9];
    const float* bhh_b  = (const float*)d_in[10];
    const float* attn_W = (const float*)d_in[11];
    const float* attn_b = (const float*)d_in[12];
    const float* centroid = (const float*)d_in[13];
    const float* beta   = (const float*)d_in[14];

    const int V = in_sizes[2] / E_;

    char* w = (char*)d_ws;
    __hip_bfloat16* f_bf  = (__hip_bfloat16*)w;  w += (size_t)T_*B_*D_*2;      // 64 MiB
    __hip_bfloat16* xg_f  = (__hip_bfloat16*)w;  w += (size_t)CH_*B_*G3_*2;    // 24 MiB
    __hip_bfloat16* xg_b  = (__hip_bfloat16*)w;  w += (size_t)CH_*B_*G3_*2;    // 24 MiB
    float*          hf32g = (float*)w;           w += (size_t)2*B_*H_*4;       // 2 MiB
    __hip_bfloat16* embbf = (__hip_bfloat16*)w;  w += (size_t)V*EP_*2;         // 30.5 MiB
    __hip_bfloat16* wihf  = (__hip_bfloat16*)w;  w += (size_t)G3_*EP_*2;
    __hip_bfloat16* wihb  = (__hip_bfloat16*)w;  w += (size_t)G3_*EP_*2;
    __hip_bfloat16* whhbf = (__hip_bfloat16*)w;  w += (size_t)2*G3_*H_*2;
    __hip_bfloat16* wat   = (__hip_bfloat16*)w;  w += (size_t)D_*D_*2;
    float*          biasc = (float*)w;           w += (size_t)2*G3_*4;
    float*          score = (float*)w;           w += (size_t)T_*B_*4;
    float*          rr2   = (float*)w;           w += (size_t)T_*B_*4;
    float*          su    = (float*)w;           w += 513*4;

    float* out  = (float*)d_out;                 // B*512
    float* hout = out + (long long)B_*D_;        // 2*B*256

    lorentz_u_kernel<<<1, 512, 0, stream>>>(centroid, su);
    prep_bias_kernel<<<2, G3_, 0, stream>>>(bih_f, bhh_f, bih_b, bhh_b, biasc);
    cast_pad_kernel<<<V,   EP_, 0, stream>>>(emb,    embbf, E_, EP_);
    cast_pad_kernel<<<G3_, EP_, 0, stream>>>(Wih_f,  wihf,  E_, EP_);
    cast_pad_kernel<<<G3_, EP_, 0, stream>>>(Wih_b,  wihb,  E_, EP_);
    cast_pad_kernel<<<G3_, H_,  0, stream>>>(Whh_f,  whhbf,            H_, H_);
    cast_pad_kernel<<<G3_, H_,  0, stream>>>(Whh_b,  whhbf + (size_t)G3_*H_, H_, H_);
    cast_pad_kernel<<<D_,  D_,  0, stream>>>(attn_W, wat,   D_, D_);

    for (int c = 0; c < T_/CH_; ++c){
        int tlo_f = c*CH_;
        int tlo_b = (T_ - CH_) - c*CH_;
        int s0 = c*CH_;
        proj_kernel<<<dim3(12, 64, 2), 256, 0, stream>>>(
            tokens, tlo_f, tlo_b, embbf, wihf, wihb, biasc, xg_f, xg_b);
        gru_chunk_kernel<<<128, 512, 0, stream>>>(
            xg_f, xg_b, tlo_f, tlo_b, f_bf, hf32g, hidden,
            whhbf, bhh_f, bhh_b, hout, s0);
    }

    attn_score_kernel<<<1024, 256, 0, stream>>>(f_bf, wat, attn_b, su, beta, score, rr2);
    pool_kernel<<<1024, 256, 0, stream>>>(f_bf, score, rr2, out);
}

// Round 15
// 616.332 us; speedup vs baseline: 1.4051x; 1.0013x over previous
//
#include <hip/hip_runtime.h>
#include <hip/hip_bf16.h>
#include <math.h>

#define T_  64
#define B_  1024
#define E_  300
#define EP_ 320     // E padded to multiple of 32
#define H_  256
#define G3_ 768
#define D_  512
#define CH_ 16      // timesteps per xg chunk / per gru launch

typedef float f32x4 __attribute__((ext_vector_type(4)));
typedef short bf16x8 __attribute__((ext_vector_type(8)));
typedef unsigned short u16x4 __attribute__((ext_vector_type(4)));

__device__ __forceinline__ float bf2f(unsigned short u){ return __uint_as_float(((unsigned)u) << 16); }
__device__ __forceinline__ unsigned short f2bf(float x){
    __hip_bfloat16 h = __float2bfloat16(x);
    return *(unsigned short*)&h;
}
__device__ __forceinline__ float fsig(float x){ return 1.0f/(1.0f + __expf(-x)); }
__device__ __forceinline__ float ftanh(float x){ return 2.0f/(1.0f + __expf(-2.0f*x)) - 1.0f; }

// ---------------------------------------------------------------------------
// centroid -> Lorentz map: su[0:512] = unit*sinh(r), su[512] = cosh(r)
// ---------------------------------------------------------------------------
__global__ void lorentz_u_kernel(const float* __restrict__ centroid,
                                 float* __restrict__ su)
{
    __shared__ float red[512];
    const int tid = threadIdx.x;
    float c = centroid[tid];
    red[tid] = c*c;
    __syncthreads();
    for (int s = 256; s > 0; s >>= 1){
        if (tid < s) red[tid] += red[tid + s];
        __syncthreads();
    }
    float rr = sqrtf(red[0]);
    su[tid] = c / rr * sinhf(rr);
    if (tid == 0) su[512] = coshf(rr);
}

// ---------------------------------------------------------------------------
// fp32 [rows][ncols] -> bf16 [rows][ncols_pad] with zero pad. block=ncols_pad.
// ---------------------------------------------------------------------------
__global__ void cast_pad_kernel(const float* __restrict__ src,
                                __hip_bfloat16* __restrict__ dst,
                                int ncols, int ncols_pad)
{
    long long r = blockIdx.x;
    int c = threadIdx.x;
    float v = (c < ncols) ? src[r*ncols + c] : 0.f;
    dst[r*ncols_pad + c] = __float2bfloat16(v);
}

// ---------------------------------------------------------------------------
// combined input bias: biasc[d][c] = bih_d[c] + (c<512 ? bhh_d[c] : 0)
// ---------------------------------------------------------------------------
__global__ void prep_bias_kernel(const float* __restrict__ bihf, const float* __restrict__ bhhf,
                                 const float* __restrict__ bihb, const float* __restrict__ bhhb,
                                 float* __restrict__ biasc)
{
    int c = threadIdx.x, d = blockIdx.x;
    const float* bih = d ? bihb : bihf;
    const float* bhh = d ? bhhb : bhhf;
    biasc[d*G3_ + c] = bih[c] + (c < 2*H_ ? bhh[c] : 0.f);
}

// ---------------------------------------------------------------------------
// MFMA projection GEMM, both dirs (z). W-RESIDENT: grid (12, 64, 2), 256 thr.
// ---------------------------------------------------------------------------
__global__ __launch_bounds__(256) void proj_kernel(
    const int* __restrict__ tokens, int tlo_f, int tlo_b,
    const __hip_bfloat16* __restrict__ embbf,
    const __hip_bfloat16* __restrict__ wihf, const __hip_bfloat16* __restrict__ wihb,
    const float* __restrict__ biasc,
    __hip_bfloat16* __restrict__ xgf, __hip_bfloat16* __restrict__ xgb)
{
    __shared__ char As[64 * 640];   // 40 KB: 64 rows x 320 bf16, swizzled 16B units
    __shared__ char Ws[64 * 640];   // 40 KB: 64 cols x 320 bf16, swizzled 16B units
    const int dir = blockIdx.z;
    const int tlo = dir ? tlo_b : tlo_f;
    const __hip_bfloat16* Wbf = dir ? wihb : wihf;
    const float* bias = biasc + dir*G3_;
    __hip_bfloat16* xg = dir ? xgb : xgf;
    const int* tok = tokens + (long long)tlo * B_;

    const int tid = threadIdx.x;
    const int n0 = blockIdx.x * 64;

    {   // stage W tile once (64 cols x 320 k): 2560 units, 10 rounds
        #pragma unroll
        for (int it = 0; it < 10; ++it){
            int idx = it*256 + tid;
            int col = idx / 40, u = idx - col*40;
            float4 v = *(const float4*)(Wbf + (size_t)(n0 + col)*EP_ + u*8);
            *(float4*)(Ws + col*640 + ((u ^ (col & 7)) * 16)) = v;
        }
    }

    const int lane = tid & 63, w = tid >> 6;
    const int g = lane >> 4, l15 = lane & 15;
    const int arow = w*16 + l15;
    const char* abase = As + arow * 640;
    const int amask = arow & 7;

    for (int rt = 0; rt < 4; ++rt){
        const int m0 = (blockIdx.y*4 + rt) * 64;
        {   // stage gathered emb rows
            int row = tid >> 2, sub = tid & 3;
            long long tk = tok[m0 + row];
            const char* src = (const char*)(embbf + tk * EP_);
            char* dst = As + row * 640;
            int xm = (row & 7);
            #pragma unroll
            for (int j = 0; j < 10; ++j){
                int slot = sub + j*4;
                float4 v = *(const float4*)(src + slot*16);
                *(float4*)(dst + ((slot ^ xm) * 16)) = v;
            }
        }
        __syncthreads();   // As ready (and Ws on first iteration)

        f32x4 acc[4];
        #pragma unroll
        for (int i = 0; i < 4; ++i) acc[i] = (f32x4){0.f,0.f,0.f,0.f};

        #pragma unroll
        for (int kc = 0; kc < 10; ++kc){
            int aslot = kc*4 + g;
            bf16x8 a = *(const bf16x8*)(abase + ((aslot ^ amask) * 16));
            #pragma unroll
            for (int ct = 0; ct < 4; ++ct){
                int cl = ct*16 + l15;
                bf16x8 b = *(const bf16x8*)(Ws + cl*640 + ((aslot ^ (cl & 7)) * 16));
                acc[ct] = __builtin_amdgcn_mfma_f32_16x16x32_bf16(a, b, acc[ct], 0, 0, 0);
            }
        }

        #pragma unroll
        for (int ct = 0; ct < 4; ++ct){
            int col = n0 + ct*16 + l15;
            float bv = bias[col];
            int rbase = m0 + w*16 + g*4;
            #pragma unroll
            for (int i = 0; i < 4; ++i)
                xg[(long long)(rbase + i)*G3_ + col] = __float2bfloat16(acc[ct][i] + bv);
        }
        __syncthreads();   // done reading As before next overwrite
    }
}

// ---------------------------------------------------------------------------
// GRU chunk kernel v8. Same as v7 except: f_bf stores are DEFERRED and
// COALESCED — previous step's h is re-read linearly from hlds (b128) and
// stored as contiguous 16B/thread rows, hidden under the MFMA chain. This
// removes the 8B x stride-1024B scatter (L2 sector write amplification +
// long store drains inside every step barrier).
// ---------------------------------------------------------------------------
__global__ __launch_bounds__(512, 1) void gru_chunk_kernel(
    const __hip_bfloat16* __restrict__ xg_f, const __hip_bfloat16* __restrict__ xg_b,
    int tlo_f, int tlo_b,
    __hip_bfloat16* __restrict__ f_bf,
    float* __restrict__ hf32g,             // [2 dir][B][H] carry between launches
    const float* __restrict__ hidden,
    const __hip_bfloat16* __restrict__ whhbf,  // [2 dir][768][256]
    const float* __restrict__ bhh_f, const float* __restrict__ bhh_b,
    float* __restrict__ hout, int s0)
{
    __shared__ char hlds[2][16 * 512];     // 2 x 8 KB, 16 rows x 256 bf16, swizzled
    __shared__ char xlds[2][16 * 1536];    // 2 x 24 KB, linear rows, rotated units
    __shared__ float blds[256];            // bhh_n for this dir
    const int bid = blockIdx.x;
    const int dir = bid & 1;
    const int b0 = (bid >> 1) * 16;
    const int tid = threadIdx.x;
    const int lane = tid & 63, w = tid >> 6;      // 8 waves
    const int g = lane >> 4, l15 = lane & 15;
    const int jq = w*32 + g*4;

    const __hip_bfloat16* xg = dir ? xg_b : xg_f;
    const int tlo = dir ? tlo_b : tlo_f;
    const float* bhh = dir ? bhh_b : bhh_f;
    const __hip_bfloat16* Wb = whhbf + (size_t)dir * G3_ * H_;
    float* hfg = hf32g + (size_t)dir * B_ * H_;
    const int b = b0 + l15;

    // coalesced-store lane mapping: thread -> (row fr, 16B unit fu)
    const int fr = tid >> 5, fu = tid & 31;

    // resident Whh fragments: [gate][tl][kc], 48 x 16B = 192 VGPR
    bf16x8 Wf[3][2][8];
    #pragma unroll
    for (int gate = 0; gate < 3; ++gate)
        #pragma unroll
        for (int tl = 0; tl < 2; ++tl)
            #pragma unroll
            for (int kc = 0; kc < 8; ++kc)
                Wf[gate][tl][kc] = *(const bf16x8*)(Wb +
                    ((size_t)(gate*H_ + w*32 + tl*16 + l15))*H_ + kc*32 + g*8);

    if (tid < 256) blds[tid] = bhh[2*H_ + tid];

    // ---- prologue: h -> hlds[0] + fp32 carry; xg(s0) -> xlds[0] ----
    const float* hsrc = (s0 == 0 ? hidden : hf32g) + (size_t)dir * B_ * H_;
    #pragma unroll
    for (int it = 0; it < 2; ++it){
        int idx = it*512 + tid;            // 1024 = 16 rows x 64 float4
        int r = idx >> 6, q = idx & 63;
        float4 v = *(const float4*)(hsrc + ((size_t)(b0 + r))*H_ + q*4);
        unsigned short t4[4] = { f2bf(v.x), f2bf(v.y), f2bf(v.z), f2bf(v.w) };
        *(uint2*)(hlds[0] + r*512 + (((q>>1) ^ (r&7))*16) + (q&1)*8) = *(uint2*)t4;
    }
    f32x4 carry[2];
    #pragma unroll
    for (int tl = 0; tl < 2; ++tl)
        carry[tl] = *(const f32x4*)&hsrc[(size_t)b*H_ + jq + tl*16];

    // rotation-swizzled async stage: LDS[r][s] = xg_row_r[(s - r) mod 96]
    auto stage_x = [&](char* dst, const __hip_bfloat16* xgt){
        #pragma unroll
        for (int i = 0; i < 3; ++i){
            int U = (i*8 + w)*64 + lane;
            int r = U / 96;
            int sbase = U - r*96;
            int usrc = sbase - r; if (usrc < 0) usrc += 96;
            const char* src = (const char*)xgt + (size_t)(b0 + r)*1536 + usrc*16;
            __builtin_amdgcn_global_load_lds(
                (const __attribute__((address_space(1))) void*)src,
                (__attribute__((address_space(3))) void*)(dst + (i*8 + w)*1024),
                16, 0, 0);
        }
    };
    {
        const int t0 = dir ? (63 - s0) : s0;
        stage_x(xlds[0], xg + (size_t)(t0 - tlo)*B_*G3_);
    }
    __syncthreads();

    int cur = 0, hc = 0;
    for (int s = s0; s < s0 + CH_; ++s){
        const int t = dir ? (63 - s) : s;

        // issue async stage of next step's xg (drains at this step's barrier)
        if (s < s0 + CH_ - 1){
            const int tn = dir ? (t - 1) : (t + 1);
            stage_x(xlds[cur ^ 1], xg + (size_t)(tn - tlo)*B_*G3_);
        }

        // deferred COALESCED f_bf store of previous step's h (from hlds[hc]);
        // hidden under the MFMA chain below.
        if (s > s0){
            const int tp = dir ? (64 - s) : (s - 1);
            float4 hv = *(const float4*)(hlds[hc] + fr*512 + ((fu ^ (fr&7))*16));
            *(float4*)((char*)f_bf + (((size_t)tp*B_ + b0 + fr)*D_ + dir*H_)*2 + fu*16) = hv;
        }

        f32x4 acc[3][2];
        #pragma unroll
        for (int gate = 0; gate < 3; ++gate)
            #pragma unroll
            for (int tl = 0; tl < 2; ++tl)
                acc[gate][tl] = (f32x4){0.f,0.f,0.f,0.f};

        // hb staged 2-at-a-time
        __builtin_amdgcn_s_setprio(1);
        #pragma unroll
        for (int kh = 0; kh < 4; ++kh){
            bf16x8 hb0 = *(const bf16x8*)(hlds[hc] + l15*512 + ((((2*kh  )*4 + g) ^ (l15&7))*16));
            bf16x8 hb1 = *(const bf16x8*)(hlds[hc] + l15*512 + ((((2*kh+1)*4 + g) ^ (l15&7))*16));
            #pragma unroll
            for (int gate = 0; gate < 3; ++gate)
                #pragma unroll
                for (int tl = 0; tl < 2; ++tl)
                    acc[gate][tl] = __builtin_amdgcn_mfma_f32_16x16x32_bf16(
                        Wf[gate][tl][2*kh], hb0, acc[gate][tl], 0, 0, 0);
            #pragma unroll
            for (int gate = 0; gate < 3; ++gate)
                #pragma unroll
                for (int tl = 0; tl < 2; ++tl)
                    acc[gate][tl] = __builtin_amdgcn_mfma_f32_16x16x32_bf16(
                        Wf[gate][tl][2*kh+1], hb1, acc[gate][tl], 0, 0, 0);
        }
        __builtin_amdgcn_s_setprio(0);

        // epilogue per j-tile: h_new -> LDS only (f_bf handled next step)
        #pragma unroll
        for (int tl = 0; tl < 2; ++tl){
            u16x4 xv[3];
            #pragma unroll
            for (int gate = 0; gate < 3; ++gate){
                int u = gate*32 + w*4 + tl*2 + (g >> 1);
                int sl = u + l15; if (sl >= 96) sl -= 96;
                xv[gate] = *(const u16x4*)(xlds[cur] + l15*1536 + sl*16 + (g & 1)*8);
            }
            f32x4 bhn = *(const f32x4*)&blds[jq + tl*16];

            unsigned short hb4[4];
            #pragma unroll
            for (int i = 0; i < 4; ++i){
                float xr = bf2f(xv[0][i]);          // includes bih_r + bhh_r
                float xz = bf2f(xv[1][i]);          // includes bih_z + bhh_z
                float xn = bf2f(xv[2][i]);          // includes bih_n
                float r_ = fsig(xr + acc[0][tl][i]);
                float z_ = fsig(xz + acc[1][tl][i]);
                float n_ = ftanh(xn + r_*(acc[2][tl][i] + bhn[i]));
                float hnew = (1.f - z_)*n_ + z_*carry[tl][i];
                carry[tl][i] = hnew;
                hb4[i] = f2bf(hnew);
            }
            int j0 = jq + tl*16;
            int slot = j0 >> 3;
            *(uint2*)(hlds[hc^1] + l15*512 + ((slot ^ (l15&7))*16) + (j0&7)*2) = *(uint2*)hb4;
            if (s == 63)
                *(f32x4*)&hout[(size_t)dir*B_*H_ + (size_t)b*H_ + j0] = carry[tl];
        }

        __syncthreads();   // drains ds writes + async xg stage + deferred store
        cur ^= 1; hc ^= 1;
    }

    // final flush: last step's h (in hlds[hc] after even number of toggles)
    {
        const int tl_ = dir ? (63 - (s0 + CH_ - 1)) : (s0 + CH_ - 1);
        float4 hv = *(const float4*)(hlds[hc] + fr*512 + ((fu ^ (fr&7))*16));
        *(float4*)((char*)f_bf + (((size_t)tl_*B_ + b0 + fr)*D_ + dir*H_)*2 + fu*16) = hv;
    }

    // persist fp32 carry
    #pragma unroll
    for (int tl = 0; tl < 2; ++tl)
        *(f32x4*)&hfg[(size_t)b*H_ + jq + tl*16] = carry[tl];
}

// ---------------------------------------------------------------------------
// MFMA attention GEMM + fused tanh/Lorentz score + rr2. 1024 blocks x 256 thr,
// 64 rows/block. W streamed in 16 chunks of 32 cols through DOUBLE-BUFFERED
// LDS (2 x 32 KB) via async global_load_lds, rotation-swizzled source.
// ---------------------------------------------------------------------------
__global__ __launch_bounds__(256) void attn_score_kernel(
    const __hip_bfloat16* __restrict__ f_bf, const __hip_bfloat16* __restrict__ Wbf,
    const float* __restrict__ attn_b, const float* __restrict__ su,
    const float* __restrict__ beta, float* __restrict__ score,
    float* __restrict__ rr2)
{
    __shared__ char WL[2][32 * 1024];   // 2 x 32 KB: 32 cols x 64 units x 16B
    const int tid = threadIdx.x;
    const int lane = tid & 63, w = tid >> 6;
    const int g = lane >> 4, l15 = lane & 15;
    const long long m0 = (long long)blockIdx.x * 64;
    const long long arow = m0 + w*16 + l15;

    bf16x8 a[16];
    const __hip_bfloat16* ap = f_bf + arow*D_;
    #pragma unroll
    for (int kc = 0; kc < 16; ++kc)
        a[kc] = *(const bf16x8*)(ap + kc*32 + g*8);

    // rr2 = sum over row of f^2
    {
        float s2 = 0.f;
        #pragma unroll
        for (int kc = 0; kc < 16; ++kc){
            const unsigned short* hb = (const unsigned short*)&a[kc];
            #pragma unroll
            for (int q = 0; q < 8; ++q){ float x = bf2f(hb[q]); s2 += x*x; }
        }
        s2 += __shfl_xor(s2, 16);
        s2 += __shfl_xor(s2, 32);
        if (g == 0) rr2[arow] = s2;
    }

    // async W chunk stage: LDS unit U=(col,slot); source unit usrc=(slot-col)&63
    auto stage_w = [&](char* dst, int nc){
        const __hip_bfloat16* wsrc = Wbf + (size_t)nc*32*D_;
        #pragma unroll
        for (int i = 0; i < 8; ++i){
            int U = i*256 + tid;
            int r = U >> 6, sl = U & 63;
            int usrc = (sl - r) & 63;
            const char* src = (const char*)(wsrc + (size_t)r*D_) + usrc*16;
            __builtin_amdgcn_global_load_lds(
                (const __attribute__((address_space(1))) void*)src,
                (__attribute__((address_space(3))) void*)(dst + U*16),
                16, 0, 0);
        }
    };

    stage_w(WL[0], 0);
    __syncthreads();

    float pdot[4] = {0,0,0,0}, pa2[4] = {0,0,0,0};
    int cur = 0;

    for (int nc = 0; nc < 16; ++nc){
        if (nc < 15) stage_w(WL[cur ^ 1], nc + 1);

        f32x4 acc[2];
        acc[0] = (f32x4){0.f,0.f,0.f,0.f};
        acc[1] = (f32x4){0.f,0.f,0.f,0.f};
        #pragma unroll
        for (int kc = 0; kc < 16; ++kc){
            int u = kc*4 + g;
            #pragma unroll
            for (int ct = 0; ct < 2; ++ct){
                int cl = ct*16 + l15;
                bf16x8 bfr = *(const bf16x8*)(WL[cur] + cl*1024 + (((u + cl) & 63)*16));
                acc[ct] = __builtin_amdgcn_mfma_f32_16x16x32_bf16(a[kc], bfr, acc[ct], 0, 0, 0);
            }
        }

        #pragma unroll
        for (int ct = 0; ct < 2; ++ct){
            int col = nc*32 + ct*16 + l15;
            float bc = attn_b[col], sc = su[col];
            #pragma unroll
            for (int i = 0; i < 4; ++i){
                float av = ftanh(acc[ct][i] + bc);
                pdot[i] += av*sc;
                pa2[i]  += av*av;
            }
        }

        __syncthreads();   // drains async stage + all waves done with WL[cur]
        cur ^= 1;
    }

    #pragma unroll
    for (int m = 1; m < 16; m <<= 1){
        #pragma unroll
        for (int i = 0; i < 4; ++i){
            pdot[i] += __shfl_xor(pdot[i], m);
            pa2[i]  += __shfl_xor(pa2[i],  m);
        }
    }
    if (l15 == 0){
        const float cu = su[512], bb = beta[0];
        #pragma unroll
        for (int i = 0; i < 4; ++i){
            long long row = m0 + w*16 + g*4 + i;
            float ra  = sqrtf(pa2[i]);
            float shc = sinhf(ra)/ra;
            float prod = cu*coshf(ra) - shc*pdot[i];
            prod = fminf(fmaxf(prod, 1.0f + 1e-7f), 1e16f);
            float dist = logf(prod) + log1pf(sqrtf(prod*prod - 1.0f + 1e-7f)/prod);
            score[row] = -bb * dist;
        }
    }
}

// ---------------------------------------------------------------------------
// per-batch softmax over T, gamma weighting, weighted fK sum (bf16 f input).
// ---------------------------------------------------------------------------
__global__ __launch_bounds__(256) void pool_kernel(
    const __hip_bfloat16* __restrict__ f_bf, const float* __restrict__ score,
    const float* __restrict__ rr2, float* __restrict__ out)
{
    __shared__ float wss[64];
    const int tid = threadIdx.x;
    const long long b = blockIdx.x;

    if (tid < 64){
        int t = tid;
        float sc = score[t*B_ + b];
        float mx = sc;
        #pragma unroll
        for (int m = 1; m < 64; m <<= 1) mx = fmaxf(mx, __shfl_xor(mx, m));
        float e = expf(sc - mx);
        float rr = sqrtf(rr2[t*B_ + b]);
        float th = tanhf(rr);
        float omt = 1.0f - th*th;
        omt = fminf(fmaxf(omt, 1e-7f), 1.0f - 1e-7f);
        float gamma = 1.0f / sqrtf(omt);
        gamma = fminf(fmaxf(gamma, 1.0f + 1e-7f), 1e16f);
        float wgt = e * gamma;
        float ssum = wgt;
        #pragma unroll
        for (int m = 1; m < 64; m <<= 1) ssum += __shfl_xor(ssum, m);
        wss[t] = (wgt / ssum) * (th / rr);
    }
    __syncthreads();

    #pragma unroll
    for (int dd = 0; dd < 2; ++dd){
        int d = tid + dd*256;
        float acc = 0.f;
        for (int t = 0; t < 64; ++t)
            acc += wss[t] * __bfloat162float(f_bf[((long long)t*B_ + b)*D_ + d]);
        out[b*D_ + d] = acc;
    }
}

// ---------------------------------------------------------------------------
extern "C" void kernel_launch(void* const* d_in, const int* in_sizes, int n_in,
                              void* d_out, int out_size, void* d_ws, size_t ws_size,
                              hipStream_t stream)
{
    const int*   tokens = (const int*)  d_in[0];
    const float* hidden = (const float*)d_in[1];
    const float* emb    = (const float*)d_in[2];
    const float* Wih_f  = (const float*)d_in[3];
    const float* Whh_f  = (const float*)d_in[4];
    const float* bih_f  = (const float*)d_in[5];
    const float* bhh_f  = (const float*)d_in[6];
    const float* Wih_b  = (const float*)d_in[7];
    const float* Whh_b  = (const float*)d_in[8];
    const float* bih_b  = (const float*)d_in[9];
    const float* bhh_b  = (const float*)d_in[10];
    const float* attn_W = (const float*)d_in[11];
    const float* attn_b = (const float*)d_in[12];
    const float* centroid = (const float*)d_in[13];
    const float* beta   = (const float*)d_in[14];

    const int V = in_sizes[2] / E_;

    char* w = (char*)d_ws;
    __hip_bfloat16* f_bf  = (__hip_bfloat16*)w;  w += (size_t)T_*B_*D_*2;      // 64 MiB
    __hip_bfloat16* xg_f  = (__hip_bfloat16*)w;  w += (size_t)CH_*B_*G3_*2;    // 24 MiB
    __hip_bfloat16* xg_b  = (__hip_bfloat16*)w;  w += (size_t)CH_*B_*G3_*2;    // 24 MiB
    float*          hf32g = (float*)w;           w += (size_t)2*B_*H_*4;       // 2 MiB
    __hip_bfloat16* embbf = (__hip_bfloat16*)w;  w += (size_t)V*EP_*2;         // 30.5 MiB
    __hip_bfloat16* wihf  = (__hip_bfloat16*)w;  w += (size_t)G3_*EP_*2;
    __hip_bfloat16* wihb  = (__hip_bfloat16*)w;  w += (size_t)G3_*EP_*2;
    __hip_bfloat16* whhbf = (__hip_bfloat16*)w;  w += (size_t)2*G3_*H_*2;
    __hip_bfloat16* wat   = (__hip_bfloat16*)w;  w += (size_t)D_*D_*2;
    float*          biasc = (float*)w;           w += (size_t)2*G3_*4;
    float*          score = (float*)w;           w += (size_t)T_*B_*4;
    float*          rr2   = (float*)w;           w += (size_t)T_*B_*4;
    float*          su    = (float*)w;           w += 513*4;

    float* out  = (float*)d_out;                 // B*512
    float* hout = out + (long long)B_*D_;        // 2*B*256

    lorentz_u_kernel<<<1, 512, 0, stream>>>(centroid, su);
    prep_bias_kernel<<<2, G3_, 0, stream>>>(bih_f, bhh_f, bih_b, bhh_b, biasc);
    cast_pad_kernel<<<V,   EP_, 0, stream>>>(emb,    embbf, E_, EP_);
    cast_pad_kernel<<<G3_, EP_, 0, stream>>>(Wih_f,  wihf,  E_, EP_);
    cast_pad_kernel<<<G3_, EP_, 0, stream>>>(Wih_b,  wihb,  E_, EP_);
    cast_pad_kernel<<<G3_, H_,  0, stream>>>(Whh_f,  whhbf,            H_, H_);
    cast_pad_kernel<<<G3_, H_,  0, stream>>>(Whh_b,  whhbf + (size_t)G3_*H_, H_, H_);
    cast_pad_kernel<<<D_,  D_,  0, stream>>>(attn_W, wat,   D_, D_);

    for (int c = 0; c < T_/CH_; ++c){
        int tlo_f = c*CH_;
        int tlo_b = (T_ - CH_) - c*CH_;
        int s0 = c*CH_;
        proj_kernel<<<dim3(12, 64, 2), 256, 0, stream>>>(
            tokens, tlo_f, tlo_b, embbf, wihf, wihb, biasc, xg_f, xg_b);
        gru_chunk_kernel<<<128, 512, 0, stream>>>(
            xg_f, xg_b, tlo_f, tlo_b, f_bf, hf32g, hidden,
            whhbf, bhh_f, bhh_b, hout, s0);
    }

    attn_score_kernel<<<1024, 256, 0, stream>>>(f_bf, wat, attn_b, su, beta, score, rr2);
    pool_kernel<<<1024, 256, 0, stream>>>(f_bf, score, rr2, out);
}

// Round 16
// 605.719 us; speedup vs baseline: 1.4297x; 1.0175x over previous
//
#include <hip/hip_runtime.h>
#include <hip/hip_bf16.h>
#include <math.h>

#define T_  64
#define B_  1024
#define E_  300
#define EP_ 320     // E padded to multiple of 32
#define H_  256
#define G3_ 768
#define D_  512
#define CH_ 16      // timesteps per xg chunk / per gru launch

typedef float f32x4 __attribute__((ext_vector_type(4)));
typedef short bf16x8 __attribute__((ext_vector_type(8)));
typedef unsigned short u16x4 __attribute__((ext_vector_type(4)));

__device__ __forceinline__ float bf2f(unsigned short u){ return __uint_as_float(((unsigned)u) << 16); }
__device__ __forceinline__ unsigned short f2bf(float x){
    __hip_bfloat16 h = __float2bfloat16(x);
    return *(unsigned short*)&h;
}
__device__ __forceinline__ float fsig(float x){ return 1.0f/(1.0f + __expf(-x)); }
__device__ __forceinline__ float ftanh(float x){ return 2.0f/(1.0f + __expf(-2.0f*x)) - 1.0f; }

// ---------------------------------------------------------------------------
// centroid -> Lorentz map: su[0:512] = unit*sinh(r), su[512] = cosh(r)
// ---------------------------------------------------------------------------
__global__ void lorentz_u_kernel(const float* __restrict__ centroid,
                                 float* __restrict__ su)
{
    __shared__ float red[512];
    const int tid = threadIdx.x;
    float c = centroid[tid];
    red[tid] = c*c;
    __syncthreads();
    for (int s = 256; s > 0; s >>= 1){
        if (tid < s) red[tid] += red[tid + s];
        __syncthreads();
    }
    float rr = sqrtf(red[0]);
    su[tid] = c / rr * sinhf(rr);
    if (tid == 0) su[512] = coshf(rr);
}

// ---------------------------------------------------------------------------
// fp32 [rows][ncols] -> bf16 [rows][ncols_pad] with zero pad. block=ncols_pad.
// ---------------------------------------------------------------------------
__global__ void cast_pad_kernel(const float* __restrict__ src,
                                __hip_bfloat16* __restrict__ dst,
                                int ncols, int ncols_pad)
{
    long long r = blockIdx.x;
    int c = threadIdx.x;
    float v = (c < ncols) ? src[r*ncols + c] : 0.f;
    dst[r*ncols_pad + c] = __float2bfloat16(v);
}

// ---------------------------------------------------------------------------
// combined input bias: biasc[d][c] = bih_d[c] + (c<512 ? bhh_d[c] : 0)
// ---------------------------------------------------------------------------
__global__ void prep_bias_kernel(const float* __restrict__ bihf, const float* __restrict__ bhhf,
                                 const float* __restrict__ bihb, const float* __restrict__ bhhb,
                                 float* __restrict__ biasc)
{
    int c = threadIdx.x, d = blockIdx.x;
    const float* bih = d ? bihb : bihf;
    const float* bhh = d ? bhhb : bhhf;
    biasc[d*G3_ + c] = bih[c] + (c < 2*H_ ? bhh[c] : 0.f);
}

// ---------------------------------------------------------------------------
// MFMA projection GEMM, both dirs (z). W-RESIDENT: grid (12, 64, 2), 256 thr.
// ---------------------------------------------------------------------------
__global__ __launch_bounds__(256) void proj_kernel(
    const int* __restrict__ tokens, int tlo_f, int tlo_b,
    const __hip_bfloat16* __restrict__ embbf,
    const __hip_bfloat16* __restrict__ wihf, const __hip_bfloat16* __restrict__ wihb,
    const float* __restrict__ biasc,
    __hip_bfloat16* __restrict__ xgf, __hip_bfloat16* __restrict__ xgb)
{
    __shared__ char As[64 * 640];   // 40 KB: 64 rows x 320 bf16, swizzled 16B units
    __shared__ char Ws[64 * 640];   // 40 KB: 64 cols x 320 bf16, swizzled 16B units
    const int dir = blockIdx.z;
    const int tlo = dir ? tlo_b : tlo_f;
    const __hip_bfloat16* Wbf = dir ? wihb : wihf;
    const float* bias = biasc + dir*G3_;
    __hip_bfloat16* xg = dir ? xgb : xgf;
    const int* tok = tokens + (long long)tlo * B_;

    const int tid = threadIdx.x;
    const int n0 = blockIdx.x * 64;

    {   // stage W tile once (64 cols x 320 k): 2560 units, 10 rounds
        #pragma unroll
        for (int it = 0; it < 10; ++it){
            int idx = it*256 + tid;
            int col = idx / 40, u = idx - col*40;
            float4 v = *(const float4*)(Wbf + (size_t)(n0 + col)*EP_ + u*8);
            *(float4*)(Ws + col*640 + ((u ^ (col & 7)) * 16)) = v;
        }
    }

    const int lane = tid & 63, w = tid >> 6;
    const int g = lane >> 4, l15 = lane & 15;
    const int arow = w*16 + l15;
    const char* abase = As + arow * 640;
    const int amask = arow & 7;

    for (int rt = 0; rt < 4; ++rt){
        const int m0 = (blockIdx.y*4 + rt) * 64;
        {   // stage gathered emb rows
            int row = tid >> 2, sub = tid & 3;
            long long tk = tok[m0 + row];
            const char* src = (const char*)(embbf + tk * EP_);
            char* dst = As + row * 640;
            int xm = (row & 7);
            #pragma unroll
            for (int j = 0; j < 10; ++j){
                int slot = sub + j*4;
                float4 v = *(const float4*)(src + slot*16);
                *(float4*)(dst + ((slot ^ xm) * 16)) = v;
            }
        }
        __syncthreads();   // As ready (and Ws on first iteration)

        f32x4 acc[4];
        #pragma unroll
        for (int i = 0; i < 4; ++i) acc[i] = (f32x4){0.f,0.f,0.f,0.f};

        #pragma unroll
        for (int kc = 0; kc < 10; ++kc){
            int aslot = kc*4 + g;
            bf16x8 a = *(const bf16x8*)(abase + ((aslot ^ amask) * 16));
            #pragma unroll
            for (int ct = 0; ct < 4; ++ct){
                int cl = ct*16 + l15;
                bf16x8 b = *(const bf16x8*)(Ws + cl*640 + ((aslot ^ (cl & 7)) * 16));
                acc[ct] = __builtin_amdgcn_mfma_f32_16x16x32_bf16(a, b, acc[ct], 0, 0, 0);
            }
        }

        #pragma unroll
        for (int ct = 0; ct < 4; ++ct){
            int col = n0 + ct*16 + l15;
            float bv = bias[col];
            int rbase = m0 + w*16 + g*4;
            #pragma unroll
            for (int i = 0; i < 4; ++i)
                xg[(long long)(rbase + i)*G3_ + col] = __float2bfloat16(acc[ct][i] + bv);
        }
        __syncthreads();   // done reading As before next overwrite
    }
}

// ---------------------------------------------------------------------------
// GRU chunk kernel v8 (round-15). 128 blocks, 512 thr, CH_ steps, 1 barrier.
// ---------------------------------------------------------------------------
__global__ __launch_bounds__(512, 1) void gru_chunk_kernel(
    const __hip_bfloat16* __restrict__ xg_f, const __hip_bfloat16* __restrict__ xg_b,
    int tlo_f, int tlo_b,
    __hip_bfloat16* __restrict__ f_bf,
    float* __restrict__ hf32g,             // [2 dir][B][H] carry between launches
    const float* __restrict__ hidden,
    const __hip_bfloat16* __restrict__ whhbf,  // [2 dir][768][256]
    const float* __restrict__ bhh_f, const float* __restrict__ bhh_b,
    float* __restrict__ hout, int s0)
{
    __shared__ char hlds[2][16 * 512];     // 2 x 8 KB, 16 rows x 256 bf16, swizzled
    __shared__ char xlds[2][16 * 1536];    // 2 x 24 KB, linear rows, rotated units
    __shared__ float blds[256];            // bhh_n for this dir
    const int bid = blockIdx.x;
    const int dir = bid & 1;
    const int b0 = (bid >> 1) * 16;
    const int tid = threadIdx.x;
    const int lane = tid & 63, w = tid >> 6;      // 8 waves
    const int g = lane >> 4, l15 = lane & 15;
    const int jq = w*32 + g*4;

    const __hip_bfloat16* xg = dir ? xg_b : xg_f;
    const int tlo = dir ? tlo_b : tlo_f;
    const float* bhh = dir ? bhh_b : bhh_f;
    const __hip_bfloat16* Wb = whhbf + (size_t)dir * G3_ * H_;
    float* hfg = hf32g + (size_t)dir * B_ * H_;
    const int b = b0 + l15;

    // coalesced-store lane mapping: thread -> (row fr, 16B unit fu)
    const int fr = tid >> 5, fu = tid & 31;

    // resident Whh fragments: [gate][tl][kc], 48 x 16B = 192 VGPR
    bf16x8 Wf[3][2][8];
    #pragma unroll
    for (int gate = 0; gate < 3; ++gate)
        #pragma unroll
        for (int tl = 0; tl < 2; ++tl)
            #pragma unroll
            for (int kc = 0; kc < 8; ++kc)
                Wf[gate][tl][kc] = *(const bf16x8*)(Wb +
                    ((size_t)(gate*H_ + w*32 + tl*16 + l15))*H_ + kc*32 + g*8);

    if (tid < 256) blds[tid] = bhh[2*H_ + tid];

    // ---- prologue: h -> hlds[0] + fp32 carry; xg(s0) -> xlds[0] ----
    const float* hsrc = (s0 == 0 ? hidden : hf32g) + (size_t)dir * B_ * H_;
    #pragma unroll
    for (int it = 0; it < 2; ++it){
        int idx = it*512 + tid;            // 1024 = 16 rows x 64 float4
        int r = idx >> 6, q = idx & 63;
        float4 v = *(const float4*)(hsrc + ((size_t)(b0 + r))*H_ + q*4);
        unsigned short t4[4] = { f2bf(v.x), f2bf(v.y), f2bf(v.z), f2bf(v.w) };
        *(uint2*)(hlds[0] + r*512 + (((q>>1) ^ (r&7))*16) + (q&1)*8) = *(uint2*)t4;
    }
    f32x4 carry[2];
    #pragma unroll
    for (int tl = 0; tl < 2; ++tl)
        carry[tl] = *(const f32x4*)&hsrc[(size_t)b*H_ + jq + tl*16];

    // rotation-swizzled async stage: LDS[r][s] = xg_row_r[(s - r) mod 96]
    auto stage_x = [&](char* dst, const __hip_bfloat16* xgt){
        #pragma unroll
        for (int i = 0; i < 3; ++i){
            int U = (i*8 + w)*64 + lane;
            int r = U / 96;
            int sbase = U - r*96;
            int usrc = sbase - r; if (usrc < 0) usrc += 96;
            const char* src = (const char*)xgt + (size_t)(b0 + r)*1536 + usrc*16;
            __builtin_amdgcn_global_load_lds(
                (const __attribute__((address_space(1))) void*)src,
                (__attribute__((address_space(3))) void*)(dst + (i*8 + w)*1024),
                16, 0, 0);
        }
    };
    {
        const int t0 = dir ? (63 - s0) : s0;
        stage_x(xlds[0], xg + (size_t)(t0 - tlo)*B_*G3_);
    }
    __syncthreads();

    int cur = 0, hc = 0;
    for (int s = s0; s < s0 + CH_; ++s){
        const int t = dir ? (63 - s) : s;

        // issue async stage of next step's xg (drains at this step's barrier)
        if (s < s0 + CH_ - 1){
            const int tn = dir ? (t - 1) : (t + 1);
            stage_x(xlds[cur ^ 1], xg + (size_t)(tn - tlo)*B_*G3_);
        }

        // deferred COALESCED f_bf store of previous step's h (from hlds[hc])
        if (s > s0){
            const int tp = dir ? (64 - s) : (s - 1);
            float4 hv = *(const float4*)(hlds[hc] + fr*512 + ((fu ^ (fr&7))*16));
            *(float4*)((char*)f_bf + (((size_t)tp*B_ + b0 + fr)*D_ + dir*H_)*2 + fu*16) = hv;
        }

        f32x4 acc[3][2];
        #pragma unroll
        for (int gate = 0; gate < 3; ++gate)
            #pragma unroll
            for (int tl = 0; tl < 2; ++tl)
                acc[gate][tl] = (f32x4){0.f,0.f,0.f,0.f};

        // hb staged 2-at-a-time
        __builtin_amdgcn_s_setprio(1);
        #pragma unroll
        for (int kh = 0; kh < 4; ++kh){
            bf16x8 hb0 = *(const bf16x8*)(hlds[hc] + l15*512 + ((((2*kh  )*4 + g) ^ (l15&7))*16));
            bf16x8 hb1 = *(const bf16x8*)(hlds[hc] + l15*512 + ((((2*kh+1)*4 + g) ^ (l15&7))*16));
            #pragma unroll
            for (int gate = 0; gate < 3; ++gate)
                #pragma unroll
                for (int tl = 0; tl < 2; ++tl)
                    acc[gate][tl] = __builtin_amdgcn_mfma_f32_16x16x32_bf16(
                        Wf[gate][tl][2*kh], hb0, acc[gate][tl], 0, 0, 0);
            #pragma unroll
            for (int gate = 0; gate < 3; ++gate)
                #pragma unroll
                for (int tl = 0; tl < 2; ++tl)
                    acc[gate][tl] = __builtin_amdgcn_mfma_f32_16x16x32_bf16(
                        Wf[gate][tl][2*kh+1], hb1, acc[gate][tl], 0, 0, 0);
        }
        __builtin_amdgcn_s_setprio(0);

        // epilogue per j-tile: h_new -> LDS only
        #pragma unroll
        for (int tl = 0; tl < 2; ++tl){
            u16x4 xv[3];
            #pragma unroll
            for (int gate = 0; gate < 3; ++gate){
                int u = gate*32 + w*4 + tl*2 + (g >> 1);
                int sl = u + l15; if (sl >= 96) sl -= 96;
                xv[gate] = *(const u16x4*)(xlds[cur] + l15*1536 + sl*16 + (g & 1)*8);
            }
            f32x4 bhn = *(const f32x4*)&blds[jq + tl*16];

            unsigned short hb4[4];
            #pragma unroll
            for (int i = 0; i < 4; ++i){
                float xr = bf2f(xv[0][i]);
                float xz = bf2f(xv[1][i]);
                float xn = bf2f(xv[2][i]);
                float r_ = fsig(xr + acc[0][tl][i]);
                float z_ = fsig(xz + acc[1][tl][i]);
                float n_ = ftanh(xn + r_*(acc[2][tl][i] + bhn[i]));
                float hnew = (1.f - z_)*n_ + z_*carry[tl][i];
                carry[tl][i] = hnew;
                hb4[i] = f2bf(hnew);
            }
            int j0 = jq + tl*16;
            int slot = j0 >> 3;
            *(uint2*)(hlds[hc^1] + l15*512 + ((slot ^ (l15&7))*16) + (j0&7)*2) = *(uint2*)hb4;
            if (s == 63)
                *(f32x4*)&hout[(size_t)dir*B_*H_ + (size_t)b*H_ + j0] = carry[tl];
        }

        __syncthreads();
        cur ^= 1; hc ^= 1;
    }

    // final flush: last step's h
    {
        const int tl_ = dir ? (63 - (s0 + CH_ - 1)) : (s0 + CH_ - 1);
        float4 hv = *(const float4*)(hlds[hc] + fr*512 + ((fu ^ (fr&7))*16));
        *(float4*)((char*)f_bf + (((size_t)tl_*B_ + b0 + fr)*D_ + dir*H_)*2 + fu*16) = hv;
    }

    // persist fp32 carry
    #pragma unroll
    for (int tl = 0; tl < 2; ++tl)
        *(f32x4*)&hfg[(size_t)b*H_ + jq + tl*16] = carry[tl];
}

// ---------------------------------------------------------------------------
// MFMA attention GEMM + fused tanh/Lorentz score + rr2. 1024 blocks x 256 thr,
// 64 rows/block. W streamed in 32 chunks of 16 cols through DOUBLE-BUFFERED
// LDS (2 x 16 KB = 32 KB -> 4 blocks/CU, 16 waves/CU) via async
// global_load_lds, rotation-swizzled source. s_setprio around MFMA.
// ---------------------------------------------------------------------------
__global__ __launch_bounds__(256) void attn_score_kernel(
    const __hip_bfloat16* __restrict__ f_bf, const __hip_bfloat16* __restrict__ Wbf,
    const float* __restrict__ attn_b, const float* __restrict__ su,
    const float* __restrict__ beta, float* __restrict__ score,
    float* __restrict__ rr2)
{
    __shared__ char WL[2][16 * 1024];   // 2 x 16 KB: 16 cols x 64 units x 16B
    const int tid = threadIdx.x;
    const int lane = tid & 63, w = tid >> 6;
    const int g = lane >> 4, l15 = lane & 15;
    const long long m0 = (long long)blockIdx.x * 64;
    const long long arow = m0 + w*16 + l15;

    bf16x8 a[16];
    const __hip_bfloat16* ap = f_bf + arow*D_;
    #pragma unroll
    for (int kc = 0; kc < 16; ++kc)
        a[kc] = *(const bf16x8*)(ap + kc*32 + g*8);

    // rr2 = sum over row of f^2
    {
        float s2 = 0.f;
        #pragma unroll
        for (int kc = 0; kc < 16; ++kc){
            const unsigned short* hb = (const unsigned short*)&a[kc];
            #pragma unroll
            for (int q = 0; q < 8; ++q){ float x = bf2f(hb[q]); s2 += x*x; }
        }
        s2 += __shfl_xor(s2, 16);
        s2 += __shfl_xor(s2, 32);
        if (g == 0) rr2[arow] = s2;
    }

    // async W chunk stage: 16 cols x 64 units; source unit usrc=(slot-col)&63
    auto stage_w = [&](char* dst, int nc){
        const __hip_bfloat16* wsrc = Wbf + (size_t)nc*16*D_;
        #pragma unroll
        for (int i = 0; i < 4; ++i){
            int U = i*256 + tid;
            int r = U >> 6, sl = U & 63;
            int usrc = (sl - r) & 63;
            const char* src = (const char*)(wsrc + (size_t)r*D_) + usrc*16;
            __builtin_amdgcn_global_load_lds(
                (const __attribute__((address_space(1))) void*)src,
                (__attribute__((address_space(3))) void*)(dst + U*16),
                16, 0, 0);
        }
    };

    stage_w(WL[0], 0);
    __syncthreads();

    float pdot[4] = {0,0,0,0}, pa2[4] = {0,0,0,0};
    int cur = 0;

    for (int nc = 0; nc < 32; ++nc){
        if (nc < 31) stage_w(WL[cur ^ 1], nc + 1);

        f32x4 acc = (f32x4){0.f,0.f,0.f,0.f};
        __builtin_amdgcn_s_setprio(1);
        #pragma unroll
        for (int kc = 0; kc < 16; ++kc){
            int u = kc*4 + g;
            bf16x8 bfr = *(const bf16x8*)(WL[cur] + l15*1024 + (((u + l15) & 63)*16));
            acc = __builtin_amdgcn_mfma_f32_16x16x32_bf16(a[kc], bfr, acc, 0, 0, 0);
        }
        __builtin_amdgcn_s_setprio(0);

        {
            int col = nc*16 + l15;
            float bc = attn_b[col], sc = su[col];
            #pragma unroll
            for (int i = 0; i < 4; ++i){
                float av = ftanh(acc[i] + bc);
                pdot[i] += av*sc;
                pa2[i]  += av*av;
            }
        }

        __syncthreads();   // drains async stage + all waves done with WL[cur]
        cur ^= 1;
    }

    #pragma unroll
    for (int m = 1; m < 16; m <<= 1){
        #pragma unroll
        for (int i = 0; i < 4; ++i){
            pdot[i] += __shfl_xor(pdot[i], m);
            pa2[i]  += __shfl_xor(pa2[i],  m);
        }
    }
    if (l15 == 0){
        const float cu = su[512], bb = beta[0];
        #pragma unroll
        for (int i = 0; i < 4; ++i){
            long long row = m0 + w*16 + g*4 + i;
            float ra  = sqrtf(pa2[i]);
            float shc = sinhf(ra)/ra;
            float prod = cu*coshf(ra) - shc*pdot[i];
            prod = fminf(fmaxf(prod, 1.0f + 1e-7f), 1e16f);
            float dist = logf(prod) + log1pf(sqrtf(prod*prod - 1.0f + 1e-7f)/prod);
            score[row] = -bb * dist;
        }
    }
}

// ---------------------------------------------------------------------------
// per-batch softmax over T, gamma weighting, weighted fK sum (bf16 f input).
// Phase 3 vectorized: 16B loads, 4-way t-split + LDS reduce (G13).
// ---------------------------------------------------------------------------
__global__ __launch_bounds__(256) void pool_kernel(
    const __hip_bfloat16* __restrict__ f_bf, const float* __restrict__ score,
    const float* __restrict__ rr2, float* __restrict__ out)
{
    __shared__ float wss[64];
    __shared__ float ps[3][64][8];
    const int tid = threadIdx.x;
    const long long b = blockIdx.x;

    if (tid < 64){
        int t = tid;
        float sc = score[t*B_ + b];
        float mx = sc;
        #pragma unroll
        for (int m = 1; m < 64; m <<= 1) mx = fmaxf(mx, __shfl_xor(mx, m));
        float e = expf(sc - mx);
        float rr = sqrtf(rr2[t*B_ + b]);
        float th = tanhf(rr);
        float omt = 1.0f - th*th;
        omt = fminf(fmaxf(omt, 1e-7f), 1.0f - 1e-7f);
        float gamma = 1.0f / sqrtf(omt);
        gamma = fminf(fmaxf(gamma, 1.0f + 1e-7f), 1e16f);
        float wgt = e * gamma;
        float ssum = wgt;
        #pragma unroll
        for (int m = 1; m < 64; m <<= 1) ssum += __shfl_xor(ssum, m);
        wss[t] = (wgt / ssum) * (th / rr);
    }
    __syncthreads();

    // phase 3: out[b][d] = sum_t wss[t]*f[t][b][d]; thread = (t-quarter, d-octet)
    const int dq = (tid & 63) * 8;
    const int tq = (tid >> 6) * 16;
    float pacc[8] = {};
    for (int tt = 0; tt < 16; ++tt){
        int t = tq + tt;
        float wv = wss[t];
        float4 v = *(const float4*)(f_bf + ((size_t)t*B_ + b)*D_ + dq);
        const unsigned short* hb = (const unsigned short*)&v;
        #pragma unroll
        for (int q = 0; q < 8; ++q) pacc[q] += wv * bf2f(hb[q]);
    }
    if (tid >= 64){
        #pragma unroll
        for (int q = 0; q < 8; ++q) ps[(tid>>6)-1][tid&63][q] = pacc[q];
    }
    __syncthreads();
    if (tid < 64){
        #pragma unroll
        for (int r = 0; r < 3; ++r)
            #pragma unroll
            for (int q = 0; q < 8; ++q) pacc[q] += ps[r][tid][q];
        float4 o0 = { pacc[0], pacc[1], pacc[2], pacc[3] };
        float4 o1 = { pacc[4], pacc[5], pacc[6], pacc[7] };
        *(float4*)&out[b*D_ + dq]     = o0;
        *(float4*)&out[b*D_ + dq + 4] = o1;
    }
}

// ---------------------------------------------------------------------------
extern "C" void kernel_launch(void* const* d_in, const int* in_sizes, int n_in,
                              void* d_out, int out_size, void* d_ws, size_t ws_size,
                              hipStream_t stream)
{
    const int*   tokens = (const int*)  d_in[0];
    const float* hidden = (const float*)d_in[1];
    const float* emb    = (const float*)d_in[2];
    const float* Wih_f  = (const float*)d_in[3];
    const float* Whh_f  = (const float*)d_in[4];
    const float* bih_f  = (const float*)d_in[5];
    const float* bhh_f  = (const float*)d_in[6];
    const float* Wih_b  = (const float*)d_in[7];
    const float* Whh_b  = (const float*)d_in[8];
    const float* bih_b  = (const float*)d_in[9];
    const float* bhh_b  = (const float*)d_in[10];
    const float* attn_W = (const float*)d_in[11];
    const float* attn_b = (const float*)d_in[12];
    const float* centroid = (const float*)d_in[13];
    const float* beta   = (const float*)d_in[14];

    const int V = in_sizes[2] / E_;

    char* w = (char*)d_ws;
    __hip_bfloat16* f_bf  = (__hip_bfloat16*)w;  w += (size_t)T_*B_*D_*2;      // 64 MiB
    __hip_bfloat16* xg_f  = (__hip_bfloat16*)w;  w += (size_t)CH_*B_*G3_*2;    // 24 MiB
    __hip_bfloat16* xg_b  = (__hip_bfloat16*)w;  w += (size_t)CH_*B_*G3_*2;    // 24 MiB
    float*          hf32g = (float*)w;           w += (size_t)2*B_*H_*4;       // 2 MiB
    __hip_bfloat16* embbf = (__hip_bfloat16*)w;  w += (size_t)V*EP_*2;         // 30.5 MiB
    __hip_bfloat16* wihf  = (__hip_bfloat16*)w;  w += (size_t)G3_*EP_*2;
    __hip_bfloat16* wihb  = (__hip_bfloat16*)w;  w += (size_t)G3_*EP_*2;
    __hip_bfloat16* whhbf = (__hip_bfloat16*)w;  w += (size_t)2*G3_*H_*2;
    __hip_bfloat16* wat   = (__hip_bfloat16*)w;  w += (size_t)D_*D_*2;
    float*          biasc = (float*)w;           w += (size_t)2*G3_*4;
    float*          score = (float*)w;           w += (size_t)T_*B_*4;
    float*          rr2   = (float*)w;           w += (size_t)T_*B_*4;
    float*          su    = (float*)w;           w += 513*4;

    float* out  = (float*)d_out;                 // B*512
    float* hout = out + (long long)B_*D_;        // 2*B*256

    lorentz_u_kernel<<<1, 512, 0, stream>>>(centroid, su);
    prep_bias_kernel<<<2, G3_, 0, stream>>>(bih_f, bhh_f, bih_b, bhh_b, biasc);
    cast_pad_kernel<<<V,   EP_, 0, stream>>>(emb,    embbf, E_, EP_);
    cast_pad_kernel<<<G3_, EP_, 0, stream>>>(Wih_f,  wihf,  E_, EP_);
    cast_pad_kernel<<<G3_, EP_, 0, stream>>>(Wih_b,  wihb,  E_, EP_);
    cast_pad_kernel<<<G3_, H_,  0, stream>>>(Whh_f,  whhbf,            H_, H_);
    cast_pad_kernel<<<G3_, H_,  0, stream>>>(Whh_b,  whhbf + (size_t)G3_*H_, H_, H_);
    cast_pad_kernel<<<D_,  D_,  0, stream>>>(attn_W, wat,   D_, D_);

    for (int c = 0; c < T_/CH_; ++c){
        int tlo_f = c*CH_;
        int tlo_b = (T_ - CH_) - c*CH_;
        int s0 = c*CH_;
        proj_kernel<<<dim3(12, 64, 2), 256, 0, stream>>>(
            tokens, tlo_f, tlo_b, embbf, wihf, wihb, biasc, xg_f, xg_b);
        gru_chunk_kernel<<<128, 512, 0, stream>>>(
            xg_f, xg_b, tlo_f, tlo_b, f_bf, hf32g, hidden,
            whhbf, bhh_f, bhh_b, hout, s0);
    }

    attn_score_kernel<<<1024, 256, 0, stream>>>(f_bf, wat, attn_b, su, beta, score, rr2);
    pool_kernel<<<1024, 256, 0, stream>>>(f_bf, score, rr2, out);
}